// Round 1
// baseline (4290.572 us; speedup 1.0000x reference)
//
#include <hip/hip_runtime.h>

// ---------------- problem constants ----------------
constexpr int NPEP = 20000, NMHC = 5000, NTCR = 100000;
constexpr int EMBD = 128, HIDD = 256;
constexpr int EPM = 200000, EMT = 400000, BB = 50000;

// ---------------- zero ----------------
__global__ void zero_kernel(float4* __restrict__ p, int n4) {
    int i = blockIdx.x * blockDim.x + threadIdx.x;
    if (i < n4) p[i] = make_float4(0.f, 0.f, 0.f, 0.f);
}

// ---------------- degree count ----------------
__global__ void count_kernel(const int* __restrict__ dst, int E, float* __restrict__ cnt) {
    int t = blockIdx.x * blockDim.x + threadIdx.x;
    if (t < E) unsafeAtomicAdd(&cnt[dst[t]], 1.0f);
}

// ---------------- edge scatter-add: acc[dst] += X[src] ----------------
template <int D>
__global__ void scatter_kernel(const int* __restrict__ src, const int* __restrict__ dst,
                               int E, const float* __restrict__ X, float* __restrict__ acc) {
    constexpr int L = D / 4;          // float4 lanes per edge
    int t = blockIdx.x * blockDim.x + threadIdx.x;
    if (t >= E * L) return;
    int e = t / L;
    int lane = t % L;
    int s = src[e], d = dst[e];
    float4 v = ((const float4*)(X + (long)s * D))[lane];
    float* a = acc + (long)d * D + lane * 4;
    unsafeAtomicAdd(a + 0, v.x);
    unsafeAtomicAdd(a + 1, v.y);
    unsafeAtomicAdd(a + 2, v.z);
    unsafeAtomicAdd(a + 3, v.w);
}

// ---------------- generic fp32 GEMM: C[M,256] = epi( A@W^T ) ----------------
// DUAL:    K-concat of (A0[K0],W0) and (A1[K1],W1)
// SCALE0:  A0 rows scaled by 1/max(cnt[row],1)   (mean aggregation)
// EPI_ACC: epilogue adds accp[row,col]/max(cnt[row],1)
template <bool DUAL, bool SCALE0, bool EPI_ACC, bool HAS_BIAS, bool RELU>
__global__ __launch_bounds__(256) void gemm_kernel(
    int M, int K0, int K1,
    const float* __restrict__ A0, const float* __restrict__ A1,
    const float* __restrict__ W0, const float* __restrict__ W1,
    const float* __restrict__ bias,
    const float* __restrict__ cnt,
    const float* __restrict__ accp,
    float* __restrict__ C) {
    __shared__ float As[8][132];
    __shared__ float Ws[8][132];
    const int tid = threadIdx.x;
    const int row0 = blockIdx.x * 128, col0 = blockIdx.y * 128;
    const int ty = tid >> 4, tx = tid & 15;   // 16x16 threads, 8x8 microtile
    const int lrow = tid >> 1;                // 0..127 (tile row / W row)
    const int lc4 = (tid & 1) * 4;            // 0 or 4

    float c[8][8];
#pragma unroll
    for (int i = 0; i < 8; i++)
#pragma unroll
        for (int j = 0; j < 8; j++) c[i][j] = 0.f;

    const int arow = row0 + lrow;
    const int wn = col0 + lrow;               // always < 256
    float scale0 = 1.f;
    if (SCALE0) {
        float cv = (arow < M) ? cnt[arow] : 1.f;
        scale0 = 1.f / fmaxf(cv, 1.f);
    }

    const int KT = K0 + (DUAL ? K1 : 0);
    for (int k0 = 0; k0 < KT; k0 += 8) {
        const int k = k0 + lc4;
        float4 av = make_float4(0.f, 0.f, 0.f, 0.f);
        if (arow < M) {
            if (!DUAL || k < K0) {
                av = *(const float4*)(A0 + (long)arow * K0 + k);
                if (SCALE0) { av.x *= scale0; av.y *= scale0; av.z *= scale0; av.w *= scale0; }
            } else {
                av = *(const float4*)(A1 + (long)arow * K1 + (k - K0));
            }
        }
        float4 wv;
        if (!DUAL || k < K0) wv = *(const float4*)(W0 + (long)wn * K0 + k);
        else                 wv = *(const float4*)(W1 + (long)wn * K1 + (k - K0));

        __syncthreads();
        As[lc4 + 0][lrow] = av.x; As[lc4 + 1][lrow] = av.y;
        As[lc4 + 2][lrow] = av.z; As[lc4 + 3][lrow] = av.w;
        Ws[lc4 + 0][lrow] = wv.x; Ws[lc4 + 1][lrow] = wv.y;
        Ws[lc4 + 2][lrow] = wv.z; Ws[lc4 + 3][lrow] = wv.w;
        __syncthreads();

#pragma unroll
        for (int kk = 0; kk < 8; kk++) {
            float a[8], b[8];
#pragma unroll
            for (int i = 0; i < 8; i++) a[i] = As[kk][ty * 8 + i];
#pragma unroll
            for (int j = 0; j < 8; j++) b[j] = Ws[kk][tx * 8 + j];
#pragma unroll
            for (int i = 0; i < 8; i++)
#pragma unroll
                for (int j = 0; j < 8; j++) c[i][j] += a[i] * b[j];
        }
    }

    // epilogue
#pragma unroll
    for (int i = 0; i < 8; i++) {
        int row = row0 + ty * 8 + i;
        if (row >= M) break;
        float es = 0.f;
        if (EPI_ACC) es = 1.f / fmaxf(cnt[row], 1.f);
        float tmp[8];
#pragma unroll
        for (int j = 0; j < 8; j++) {
            int col = col0 + tx * 8 + j;
            float v = c[i][j];
            if (HAS_BIAS) v += bias[col];
            if (EPI_ACC) v += accp[(long)row * 256 + col] * es;
            if (RELU) v = fmaxf(v, 0.f);
            tmp[j] = v;
        }
        float* cp = C + (long)row * 256 + col0 + tx * 8;
        *(float4*)(cp) = make_float4(tmp[0], tmp[1], tmp[2], tmp[3]);
        *(float4*)(cp + 4) = make_float4(tmp[4], tmp[5], tmp[6], tmp[7]);
    }
}

// ---------------- fused head: gather z -> GEMM(768->256) -> relu -> dot(W2) ----------------
__global__ __launch_bounds__(256) void head_kernel(
    const float* __restrict__ hp, const float* __restrict__ hm, const float* __restrict__ ht,
    const int* __restrict__ pp, const int* __restrict__ pm, const int* __restrict__ pt,
    const float* __restrict__ W1, const float* __restrict__ b1,
    const float* __restrict__ W2, const float* __restrict__ b2,
    float* __restrict__ out) {
    __shared__ float As[16][68];
    __shared__ float Ws[16][260];
    __shared__ float b1s[256], W2s[256];
    __shared__ int rp[64], rm[64], rt[64];
    __shared__ float partial[64][33];

    const int tid = threadIdx.x;
    const int row0 = blockIdx.x * 64;
    if (tid < 64) {
        int i = row0 + tid;
        int ii = (i < BB) ? i : 0;
        rp[tid] = pp[ii]; rm[tid] = pm[ii]; rt[tid] = pt[ii];
    }
    b1s[tid] = b1[tid];
    W2s[tid] = W2[tid];
    __syncthreads();

    float c[8][8];
#pragma unroll
    for (int i = 0; i < 8; i++)
#pragma unroll
        for (int j = 0; j < 8; j++) c[i][j] = 0.f;

    const int ty = tid >> 5, tx = tid & 31;  // 8x32 threads; rows ty*8.., cols tx+32j
    const int lrow = tid >> 2;               // 0..63
    const int lc4 = (tid & 3) * 4;           // 0,4,8,12

    for (int kt = 0; kt < 768; kt += 16) {
        int k = kt + lc4;
        const float* srcrow;
        int kk;
        if (k < 256)      { srcrow = hp + (long)rp[lrow] * 256; kk = k; }
        else if (k < 512) { srcrow = hm + (long)rm[lrow] * 256; kk = k - 256; }
        else              { srcrow = ht + (long)rt[lrow] * 256; kk = k - 512; }
        float4 av = *(const float4*)(srcrow + kk);
        const float* wrow = W1 + (long)tid * 768 + kt;
        float4 w0 = *(const float4*)(wrow + 0);
        float4 w1 = *(const float4*)(wrow + 4);
        float4 w2 = *(const float4*)(wrow + 8);
        float4 w3 = *(const float4*)(wrow + 12);

        __syncthreads();
        As[lc4 + 0][lrow] = av.x; As[lc4 + 1][lrow] = av.y;
        As[lc4 + 2][lrow] = av.z; As[lc4 + 3][lrow] = av.w;
        Ws[0][tid] = w0.x;  Ws[1][tid] = w0.y;  Ws[2][tid] = w0.z;  Ws[3][tid] = w0.w;
        Ws[4][tid] = w1.x;  Ws[5][tid] = w1.y;  Ws[6][tid] = w1.z;  Ws[7][tid] = w1.w;
        Ws[8][tid] = w2.x;  Ws[9][tid] = w2.y;  Ws[10][tid] = w2.z; Ws[11][tid] = w2.w;
        Ws[12][tid] = w3.x; Ws[13][tid] = w3.y; Ws[14][tid] = w3.z; Ws[15][tid] = w3.w;
        __syncthreads();

#pragma unroll
        for (int kk2 = 0; kk2 < 16; kk2++) {
            float a[8], b[8];
#pragma unroll
            for (int i = 0; i < 8; i++) a[i] = As[kk2][ty * 8 + i];
#pragma unroll
            for (int j = 0; j < 8; j++) b[j] = Ws[kk2][tx + 32 * j];
#pragma unroll
            for (int i = 0; i < 8; i++)
#pragma unroll
                for (int j = 0; j < 8; j++) c[i][j] += a[i] * b[j];
        }
    }

    // epilogue: relu(c + b1) dot W2, reduce over columns
#pragma unroll
    for (int i = 0; i < 8; i++) {
        float p = 0.f;
#pragma unroll
        for (int j = 0; j < 8; j++) {
            int col = tx + 32 * j;
            float h = c[i][j] + b1s[col];
            h = fmaxf(h, 0.f);
            p += h * W2s[col];
        }
        partial[ty * 8 + i][tx] = p;
    }
    __syncthreads();
    if (tid < 64) {
        float s = 0.f;
#pragma unroll
        for (int j = 0; j < 32; j++) s += partial[tid][j];
        int i = row0 + tid;
        if (i < BB) out[i] = s + b2[0];
    }
}

// ---------------- launch ----------------
extern "C" void kernel_launch(void* const* d_in, const int* in_sizes, int n_in,
                              void* d_out, int out_size, void* d_ws, size_t ws_size,
                              hipStream_t stream) {
    const float* emb_pep = (const float*)d_in[0];
    const float* emb_mhc = (const float*)d_in[1];
    const float* emb_tcr = (const float*)d_in[2];
    const int* src_pm = (const int*)d_in[3];
    const int* dst_pm = (const int*)d_in[4];
    const int* src_mt = (const int*)d_in[5];
    const int* dst_mt = (const int*)d_in[6];
    const int* pack_pep = (const int*)d_in[7];
    const int* pack_mhc = (const int*)d_in[8];
    const int* pack_tcr = (const int*)d_in[9];
    const float* l1_pm_Wl = (const float*)d_in[10];
    const float* l1_pm_bl = (const float*)d_in[11];
    const float* l1_pm_Wr = (const float*)d_in[12];
    const float* l1_mt_Wl = (const float*)d_in[13];
    const float* l1_mt_bl = (const float*)d_in[14];
    const float* l1_mt_Wr = (const float*)d_in[15];
    const float* l2_pm_Wl = (const float*)d_in[16];
    const float* l2_pm_bl = (const float*)d_in[17];
    const float* l2_pm_Wr = (const float*)d_in[18];
    const float* l2_mt_Wl = (const float*)d_in[19];
    const float* l2_mt_bl = (const float*)d_in[20];
    const float* l2_mt_Wr = (const float*)d_in[21];
    const float* proj_W = (const float*)d_in[22];
    const float* proj_b = (const float*)d_in[23];
    const float* head_W1 = (const float*)d_in[24];
    const float* head_b1 = (const float*)d_in[25];
    const float* head_W2 = (const float*)d_in[26];
    const float* head_b2 = (const float*)d_in[27];
    float* out = (float*)d_out;

    // workspace layout (floats). zeroed region first.
    float* ws = (float*)d_ws;
    float* cnt_pm = ws;                        // 5000
    float* agg_pm = cnt_pm + 5000;             // 5000*128   = 640000
    float* cnt_mt = agg_pm + 640000;           // 100000
    float* tcr1   = cnt_mt + 100000;           // 100000*256 = 25600000 (acc then output, in-place)
    float* tcr2   = tcr1 + 25600000;           // 25600000 (acc then output)
    float* mhc1   = tcr2 + 25600000;           // 5000*256 = 1280000
    float* mhc2   = mhc1 + 1280000;
    float* Z1     = mhc2 + 1280000;
    float* Z2     = Z1 + 1280000;
    float* hp_all = Z2 + 1280000;              // 20000*256 = 5120000

    const int ZFLOATS = 5000 + 640000 + 100000 + 25600000 + 25600000; // 51,945,000
    const int n4 = ZFLOATS / 4;

    zero_kernel<<<(n4 + 255) / 256, 256, 0, stream>>>((float4*)ws, n4);
    count_kernel<<<(EPM + 255) / 256, 256, 0, stream>>>(dst_pm, EPM, cnt_pm);
    count_kernel<<<(EMT + 255) / 256, 256, 0, stream>>>(dst_mt, EMT, cnt_mt);

    // agg_pm = segsum(emb_pep[src_pm] -> dst_pm)
    scatter_kernel<128><<<(EPM * 32 + 255) / 256, 256, 0, stream>>>(src_pm, dst_pm, EPM, emb_pep, agg_pm);

    dim3 g5((NMHC + 127) / 128, 2), g20((NPEP + 127) / 128, 2), g100((NTCR + 127) / 128, 2);

    // mhc1 = relu( mean_pm @ l1_pm_Wl^T + bl + emb_mhc @ l1_pm_Wr^T )
    gemm_kernel<true, true, false, true, true><<<g5, 256, 0, stream>>>(
        NMHC, 128, 128, agg_pm, emb_mhc, l1_pm_Wl, l1_pm_Wr, l1_pm_bl, cnt_pm, nullptr, mhc1);
    // Z1 = emb_mhc @ l1_mt_Wl^T
    gemm_kernel<false, false, false, false, false><<<g5, 256, 0, stream>>>(
        NMHC, 128, 0, emb_mhc, nullptr, l1_mt_Wl, nullptr, nullptr, nullptr, nullptr, Z1);
    // tcr1_acc = segsum(Z1[src_mt] -> dst_mt)
    scatter_kernel<256><<<(EMT * 64 + 255) / 256, 256, 0, stream>>>(src_mt, dst_mt, EMT, Z1, tcr1);
    // mhc2 = relu( mean_pm @ l2_pm_Wl^T + bl + mhc1 @ l2_pm_Wr^T )
    gemm_kernel<true, true, false, true, true><<<g5, 256, 0, stream>>>(
        NMHC, 128, 256, agg_pm, mhc1, l2_pm_Wl, l2_pm_Wr, l2_pm_bl, cnt_pm, nullptr, mhc2);
    // Z2 = mhc1 @ l2_mt_Wl^T
    gemm_kernel<false, false, false, false, false><<<g5, 256, 0, stream>>>(
        NMHC, 256, 0, mhc1, nullptr, l2_mt_Wl, nullptr, nullptr, nullptr, nullptr, Z2);
    // tcr2_acc = segsum(Z2[src_mt] -> dst_mt)
    scatter_kernel<256><<<(EMT * 64 + 255) / 256, 256, 0, stream>>>(src_mt, dst_mt, EMT, Z2, tcr2);
    // tcr1 = relu( emb_tcr @ l1_mt_Wr^T + bl + tcr1_acc/cnt )   (in-place epilogue)
    gemm_kernel<false, false, true, true, true><<<g100, 256, 0, stream>>>(
        NTCR, 128, 0, emb_tcr, nullptr, l1_mt_Wr, nullptr, l1_mt_bl, cnt_mt, tcr1, tcr1);
    // tcr2 = relu( tcr1 @ l2_mt_Wr^T + bl + tcr2_acc/cnt )
    gemm_kernel<false, false, true, true, true><<<g100, 256, 0, stream>>>(
        NTCR, 256, 0, tcr1, nullptr, l2_mt_Wr, nullptr, l2_mt_bl, cnt_mt, tcr2, tcr2);
    // hp_all = emb_pep @ proj_W^T + proj_b
    gemm_kernel<false, false, false, true, false><<<g20, 256, 0, stream>>>(
        NPEP, 128, 0, emb_pep, nullptr, proj_W, nullptr, proj_b, nullptr, nullptr, hp_all);
    // head
    head_kernel<<<(BB + 63) / 64, 256, 0, stream>>>(
        hp_all, mhc2, tcr2, pack_pep, pack_mhc, pack_tcr, head_W1, head_b1, head_W2, head_b2, out);
}

// Round 2
// 1346.201 us; speedup vs baseline: 3.1872x; 3.1872x over previous
//
#include <hip/hip_runtime.h>

// ---------------- problem constants ----------------
constexpr int NPEP = 20000, NMHC = 5000, NTCR = 100000;
constexpr int EPM = 200000, EMT = 400000, BB = 50000;

// ---------------- zero ints ----------------
__global__ void zero_int_kernel(int* __restrict__ p, int n) {
    int i = blockIdx.x * blockDim.x + threadIdx.x;
    if (i < n) p[i] = 0;
}

// ---------------- degree histogram ----------------
__global__ void hist_kernel(const int* __restrict__ dst, int E, int* __restrict__ deg) {
    int t = blockIdx.x * blockDim.x + threadIdx.x;
    if (t < E) atomicAdd(&deg[dst[t]], 1);
}

// ---------------- single-block exclusive scan: rp[0..n], rp[n]=total ----------------
__global__ __launch_bounds__(1024) void scan_kernel(const int* __restrict__ deg, int n,
                                                    int* __restrict__ rp) {
    __shared__ int sums[1024];
    const int tid = threadIdx.x;
    const int chunk = (n + 1023) / 1024;
    const int s0 = tid * chunk, s1 = min(s0 + chunk, n);
    int s = 0;
    for (int i = s0; i < s1; i++) s += deg[i];
    sums[tid] = s;
    __syncthreads();
    for (int off = 1; off < 1024; off <<= 1) {
        int v = (tid >= off) ? sums[tid - off] : 0;
        __syncthreads();
        sums[tid] += v;
        __syncthreads();
    }
    int base = (tid > 0) ? sums[tid - 1] : 0;
    for (int i = s0; i < s1; i++) { rp[i] = base; base += deg[i]; }
    if (tid == 1023) rp[n] = sums[1023];
}

// ---------------- CSR fill ----------------
__global__ void fill_kernel(const int* __restrict__ src, const int* __restrict__ dst, int E,
                            const int* __restrict__ rp, int* __restrict__ cur,
                            int* __restrict__ csr_src) {
    int t = blockIdx.x * blockDim.x + threadIdx.x;
    if (t >= E) return;
    int d = dst[t];
    int pos = atomicAdd(&cur[d], 1);
    csr_src[rp[d] + pos] = src[t];
}

// ---------------- cnt[i] = rp[i+1]-rp[i] (as float) ----------------
__global__ void cnt_kernel(const int* __restrict__ rp, int n, float* __restrict__ cnt) {
    int i = blockIdx.x * blockDim.x + threadIdx.x;
    if (i < n) cnt[i] = (float)(rp[i + 1] - rp[i]);
}

// ---------------- pull gather: acc[r] = sum_{e in row r} X[csr_src[e]] ----------------
template <int D>
__global__ __launch_bounds__(256) void gather_kernel(const int* __restrict__ rp,
                                                     const int* __restrict__ csr_src,
                                                     const float* __restrict__ X,
                                                     float* __restrict__ acc, int n) {
    constexpr int LPR = D / 4;            // lanes per row
    constexpr int RPB = 256 / LPR;        // rows per block
    const int tid = threadIdx.x;
    const int r = blockIdx.x * RPB + tid / LPR;
    const int lane = tid % LPR;
    if (r >= n) return;
    const int e0 = rp[r], e1 = rp[r + 1];
    float4 s = make_float4(0.f, 0.f, 0.f, 0.f);
    for (int e = e0; e < e1; e++) {
        const int sidx = csr_src[e];
        float4 v = ((const float4*)(X + (long)sidx * D))[lane];
        s.x += v.x; s.y += v.y; s.z += v.z; s.w += v.w;
    }
    ((float4*)(acc + (long)r * D))[lane] = s;
}

// ---------------- generic fp32 GEMM: C[M,256] = epi( A@W^T ) ----------------
template <bool DUAL, bool SCALE0, bool EPI_ACC, bool HAS_BIAS, bool RELU>
__global__ __launch_bounds__(256) void gemm_kernel(
    int M, int K0, int K1,
    const float* __restrict__ A0, const float* __restrict__ A1,
    const float* __restrict__ W0, const float* __restrict__ W1,
    const float* __restrict__ bias,
    const float* __restrict__ cnt,
    const float* __restrict__ accp,
    float* __restrict__ C) {
    __shared__ float As[8][132];
    __shared__ float Ws[8][132];
    const int tid = threadIdx.x;
    const int row0 = blockIdx.x * 128, col0 = blockIdx.y * 128;
    const int ty = tid >> 4, tx = tid & 15;
    const int lrow = tid >> 1;
    const int lc4 = (tid & 1) * 4;

    float c[8][8];
#pragma unroll
    for (int i = 0; i < 8; i++)
#pragma unroll
        for (int j = 0; j < 8; j++) c[i][j] = 0.f;

    const int arow = row0 + lrow;
    const int wn = col0 + lrow;
    float scale0 = 1.f;
    if (SCALE0) {
        float cv = (arow < M) ? cnt[arow] : 1.f;
        scale0 = 1.f / fmaxf(cv, 1.f);
    }

    const int KT = K0 + (DUAL ? K1 : 0);
    for (int k0 = 0; k0 < KT; k0 += 8) {
        const int k = k0 + lc4;
        float4 av = make_float4(0.f, 0.f, 0.f, 0.f);
        if (arow < M) {
            if (!DUAL || k < K0) {
                av = *(const float4*)(A0 + (long)arow * K0 + k);
                if (SCALE0) { av.x *= scale0; av.y *= scale0; av.z *= scale0; av.w *= scale0; }
            } else {
                av = *(const float4*)(A1 + (long)arow * K1 + (k - K0));
            }
        }
        float4 wv;
        if (!DUAL || k < K0) wv = *(const float4*)(W0 + (long)wn * K0 + k);
        else                 wv = *(const float4*)(W1 + (long)wn * K1 + (k - K0));

        __syncthreads();
        As[lc4 + 0][lrow] = av.x; As[lc4 + 1][lrow] = av.y;
        As[lc4 + 2][lrow] = av.z; As[lc4 + 3][lrow] = av.w;
        Ws[lc4 + 0][lrow] = wv.x; Ws[lc4 + 1][lrow] = wv.y;
        Ws[lc4 + 2][lrow] = wv.z; Ws[lc4 + 3][lrow] = wv.w;
        __syncthreads();

#pragma unroll
        for (int kk = 0; kk < 8; kk++) {
            float a[8], b[8];
#pragma unroll
            for (int i = 0; i < 8; i++) a[i] = As[kk][ty * 8 + i];
#pragma unroll
            for (int j = 0; j < 8; j++) b[j] = Ws[kk][tx * 8 + j];
#pragma unroll
            for (int i = 0; i < 8; i++)
#pragma unroll
                for (int j = 0; j < 8; j++) c[i][j] += a[i] * b[j];
        }
    }

#pragma unroll
    for (int i = 0; i < 8; i++) {
        int row = row0 + ty * 8 + i;
        if (row >= M) break;
        float es = 0.f;
        if (EPI_ACC) es = 1.f / fmaxf(cnt[row], 1.f);
        float tmp[8];
#pragma unroll
        for (int j = 0; j < 8; j++) {
            int col = col0 + tx * 8 + j;
            float v = c[i][j];
            if (HAS_BIAS) v += bias[col];
            if (EPI_ACC) v += accp[(long)row * 256 + col] * es;
            if (RELU) v = fmaxf(v, 0.f);
            tmp[j] = v;
        }
        float* cp = C + (long)row * 256 + col0 + tx * 8;
        *(float4*)(cp) = make_float4(tmp[0], tmp[1], tmp[2], tmp[3]);
        *(float4*)(cp + 4) = make_float4(tmp[4], tmp[5], tmp[6], tmp[7]);
    }
}

// ---------------- fused head ----------------
__global__ __launch_bounds__(256) void head_kernel(
    const float* __restrict__ hp, const float* __restrict__ hm, const float* __restrict__ ht,
    const int* __restrict__ pp, const int* __restrict__ pm, const int* __restrict__ pt,
    const float* __restrict__ W1, const float* __restrict__ b1,
    const float* __restrict__ W2, const float* __restrict__ b2,
    float* __restrict__ out) {
    __shared__ float As[16][68];
    __shared__ float Ws[16][260];
    __shared__ float b1s[256], W2s[256];
    __shared__ int rp[64], rm[64], rt[64];
    __shared__ float partial[64][33];

    const int tid = threadIdx.x;
    const int row0 = blockIdx.x * 64;
    if (tid < 64) {
        int i = row0 + tid;
        int ii = (i < BB) ? i : 0;
        rp[tid] = pp[ii]; rm[tid] = pm[ii]; rt[tid] = pt[ii];
    }
    b1s[tid] = b1[tid];
    W2s[tid] = W2[tid];
    __syncthreads();

    float c[8][8];
#pragma unroll
    for (int i = 0; i < 8; i++)
#pragma unroll
        for (int j = 0; j < 8; j++) c[i][j] = 0.f;

    const int ty = tid >> 5, tx = tid & 31;
    const int lrow = tid >> 2;
    const int lc4 = (tid & 3) * 4;

    for (int kt = 0; kt < 768; kt += 16) {
        int k = kt + lc4;
        const float* srcrow;
        int kk;
        if (k < 256)      { srcrow = hp + (long)rp[lrow] * 256; kk = k; }
        else if (k < 512) { srcrow = hm + (long)rm[lrow] * 256; kk = k - 256; }
        else              { srcrow = ht + (long)rt[lrow] * 256; kk = k - 512; }
        float4 av = *(const float4*)(srcrow + kk);
        const float* wrow = W1 + (long)tid * 768 + kt;
        float4 w0 = *(const float4*)(wrow + 0);
        float4 w1 = *(const float4*)(wrow + 4);
        float4 w2 = *(const float4*)(wrow + 8);
        float4 w3 = *(const float4*)(wrow + 12);

        __syncthreads();
        As[lc4 + 0][lrow] = av.x; As[lc4 + 1][lrow] = av.y;
        As[lc4 + 2][lrow] = av.z; As[lc4 + 3][lrow] = av.w;
        Ws[0][tid] = w0.x;  Ws[1][tid] = w0.y;  Ws[2][tid] = w0.z;  Ws[3][tid] = w0.w;
        Ws[4][tid] = w1.x;  Ws[5][tid] = w1.y;  Ws[6][tid] = w1.z;  Ws[7][tid] = w1.w;
        Ws[8][tid] = w2.x;  Ws[9][tid] = w2.y;  Ws[10][tid] = w2.z; Ws[11][tid] = w2.w;
        Ws[12][tid] = w3.x; Ws[13][tid] = w3.y; Ws[14][tid] = w3.z; Ws[15][tid] = w3.w;
        __syncthreads();

#pragma unroll
        for (int kk2 = 0; kk2 < 16; kk2++) {
            float a[8], b[8];
#pragma unroll
            for (int i = 0; i < 8; i++) a[i] = As[kk2][ty * 8 + i];
#pragma unroll
            for (int j = 0; j < 8; j++) b[j] = Ws[kk2][tx + 32 * j];
#pragma unroll
            for (int i = 0; i < 8; i++)
#pragma unroll
                for (int j = 0; j < 8; j++) c[i][j] += a[i] * b[j];
        }
    }

#pragma unroll
    for (int i = 0; i < 8; i++) {
        float p = 0.f;
#pragma unroll
        for (int j = 0; j < 8; j++) {
            int col = tx + 32 * j;
            float h = c[i][j] + b1s[col];
            h = fmaxf(h, 0.f);
            p += h * W2s[col];
        }
        partial[ty * 8 + i][tx] = p;
    }
    __syncthreads();
    if (tid < 64) {
        float s = 0.f;
#pragma unroll
        for (int j = 0; j < 32; j++) s += partial[tid][j];
        int i = row0 + tid;
        if (i < BB) out[i] = s + b2[0];
    }
}

// ---------------- launch ----------------
extern "C" void kernel_launch(void* const* d_in, const int* in_sizes, int n_in,
                              void* d_out, int out_size, void* d_ws, size_t ws_size,
                              hipStream_t stream) {
    const float* emb_pep = (const float*)d_in[0];
    const float* emb_mhc = (const float*)d_in[1];
    const float* emb_tcr = (const float*)d_in[2];
    const int* src_pm = (const int*)d_in[3];
    const int* dst_pm = (const int*)d_in[4];
    const int* src_mt = (const int*)d_in[5];
    const int* dst_mt = (const int*)d_in[6];
    const int* pack_pep = (const int*)d_in[7];
    const int* pack_mhc = (const int*)d_in[8];
    const int* pack_tcr = (const int*)d_in[9];
    const float* l1_pm_Wl = (const float*)d_in[10];
    const float* l1_pm_bl = (const float*)d_in[11];
    const float* l1_pm_Wr = (const float*)d_in[12];
    const float* l1_mt_Wl = (const float*)d_in[13];
    const float* l1_mt_bl = (const float*)d_in[14];
    const float* l1_mt_Wr = (const float*)d_in[15];
    const float* l2_pm_Wl = (const float*)d_in[16];
    const float* l2_pm_bl = (const float*)d_in[17];
    const float* l2_pm_Wr = (const float*)d_in[18];
    const float* l2_mt_Wl = (const float*)d_in[19];
    const float* l2_mt_bl = (const float*)d_in[20];
    const float* l2_mt_Wr = (const float*)d_in[21];
    const float* proj_W = (const float*)d_in[22];
    const float* proj_b = (const float*)d_in[23];
    const float* head_W1 = (const float*)d_in[24];
    const float* head_b1 = (const float*)d_in[25];
    const float* head_W2 = (const float*)d_in[26];
    const float* head_b2 = (const float*)d_in[27];
    float* out = (float*)d_out;

    // ---------------- workspace layout ----------------
    int* ib = (int*)d_ws;
    int* deg_pm = ib;                 // 5000
    int* cur_pm = ib + 5000;          // 5000
    int* deg_mt = ib + 10000;         // 100000
    int* cur_mt = ib + 110000;        // 100000   [zero region: first 210000 ints]
    int* rp_pm  = ib + 210000;        // 5001 (pad 5008)
    int* rp_mt  = ib + 215008;        // 100001 (pad 100008)
    int* csr_pm = ib + 315016;        // 200000
    int* csr_mt = ib + 515016;        // 400000  -> ints end at 915016

    float* f = (float*)(ib + 915016);
    float* cnt_pm = f;                // 5000
    float* cnt_mt = f + 5000;         // 100000
    float* agg_pm = f + 105000;       // 640000
    float* Z      = f + 745000;       // 1280000 (reused for Z1 then Z2)
    float* mhc1   = f + 2025000;      // 1280000
    float* mhc2   = f + 3305000;      // 1280000
    float* hp_all = f + 4585000;      // 5120000
    float* tcr1   = f + 9705000;      // 25600000
    float* tcr2   = f + 35305000;     // 25600000 -> ends at 60905000 floats (~247 MB total)

    // ---------------- CSR build ----------------
    zero_int_kernel<<<(210000 + 255) / 256, 256, 0, stream>>>(ib, 210000);
    hist_kernel<<<(EPM + 255) / 256, 256, 0, stream>>>(dst_pm, EPM, deg_pm);
    hist_kernel<<<(EMT + 255) / 256, 256, 0, stream>>>(dst_mt, EMT, deg_mt);
    scan_kernel<<<1, 1024, 0, stream>>>(deg_pm, NMHC, rp_pm);
    scan_kernel<<<1, 1024, 0, stream>>>(deg_mt, NTCR, rp_mt);
    fill_kernel<<<(EPM + 255) / 256, 256, 0, stream>>>(src_pm, dst_pm, EPM, rp_pm, cur_pm, csr_pm);
    fill_kernel<<<(EMT + 255) / 256, 256, 0, stream>>>(src_mt, dst_mt, EMT, rp_mt, cur_mt, csr_mt);
    cnt_kernel<<<(NMHC + 255) / 256, 256, 0, stream>>>(rp_pm, NMHC, cnt_pm);
    cnt_kernel<<<(NTCR + 255) / 256, 256, 0, stream>>>(rp_mt, NTCR, cnt_mt);

    // ---------------- graph + MLP pipeline ----------------
    dim3 g5((NMHC + 127) / 128, 2), g20((NPEP + 127) / 128, 2), g100((NTCR + 127) / 128, 2);

    // agg_pm = segsum(emb_pep[src_pm] -> dst_pm)   [pull]
    gather_kernel<128><<<(NMHC + 7) / 8, 256, 0, stream>>>(rp_pm, csr_pm, emb_pep, agg_pm, NMHC);

    // mhc1 = relu( mean_pm @ l1_pm_Wl^T + bl + emb_mhc @ l1_pm_Wr^T )
    gemm_kernel<true, true, false, true, true><<<g5, 256, 0, stream>>>(
        NMHC, 128, 128, agg_pm, emb_mhc, l1_pm_Wl, l1_pm_Wr, l1_pm_bl, cnt_pm, nullptr, mhc1);
    // Z = emb_mhc @ l1_mt_Wl^T
    gemm_kernel<false, false, false, false, false><<<g5, 256, 0, stream>>>(
        NMHC, 128, 0, emb_mhc, nullptr, l1_mt_Wl, nullptr, nullptr, nullptr, nullptr, Z);
    // tcr1_acc = segsum(Z[src_mt] -> dst_mt)   [pull]
    gather_kernel<256><<<(NTCR + 3) / 4, 256, 0, stream>>>(rp_mt, csr_mt, Z, tcr1, NTCR);
    // mhc2 = relu( mean_pm @ l2_pm_Wl^T + bl + mhc1 @ l2_pm_Wr^T )
    gemm_kernel<true, true, false, true, true><<<g5, 256, 0, stream>>>(
        NMHC, 128, 256, agg_pm, mhc1, l2_pm_Wl, l2_pm_Wr, l2_pm_bl, cnt_pm, nullptr, mhc2);
    // Z = mhc1 @ l2_mt_Wl^T   (reuse buffer; previous gather already consumed it)
    gemm_kernel<false, false, false, false, false><<<g5, 256, 0, stream>>>(
        NMHC, 256, 0, mhc1, nullptr, l2_mt_Wl, nullptr, nullptr, nullptr, nullptr, Z);
    // tcr2_acc = segsum(Z[src_mt] -> dst_mt)   [pull]
    gather_kernel<256><<<(NTCR + 3) / 4, 256, 0, stream>>>(rp_mt, csr_mt, Z, tcr2, NTCR);
    // tcr1 = relu( emb_tcr @ l1_mt_Wr^T + bl + tcr1_acc/cnt )
    gemm_kernel<false, false, true, true, true><<<g100, 256, 0, stream>>>(
        NTCR, 128, 0, emb_tcr, nullptr, l1_mt_Wr, nullptr, l1_mt_bl, cnt_mt, tcr1, tcr1);
    // tcr2 = relu( tcr1 @ l2_mt_Wr^T + bl + tcr2_acc/cnt )
    gemm_kernel<false, false, true, true, true><<<g100, 256, 0, stream>>>(
        NTCR, 256, 0, tcr1, nullptr, l2_mt_Wr, nullptr, l2_mt_bl, cnt_mt, tcr2, tcr2);
    // hp_all = emb_pep @ proj_W^T + proj_b
    gemm_kernel<false, false, false, true, false><<<g20, 256, 0, stream>>>(
        NPEP, 128, 0, emb_pep, nullptr, proj_W, nullptr, proj_b, nullptr, nullptr, hp_all);
    // head
    head_kernel<<<(BB + 63) / 64, 256, 0, stream>>>(
        hp_all, mhc2, tcr2, pack_pep, pack_mhc, pack_tcr, head_W1, head_b1, head_W2, head_b2, out);
}

// Round 3
// 857.589 us; speedup vs baseline: 5.0031x; 1.5697x over previous
//
#include <hip/hip_runtime.h>

// ---------------- problem constants ----------------
constexpr int NPEP = 20000, NMHC = 5000, NTCR = 100000;
constexpr int EPM = 200000, EMT = 400000, BB = 50000;

typedef __attribute__((ext_vector_type(8))) short bf16x8;
typedef __attribute__((ext_vector_type(4))) float f32x4;

__device__ inline ushort f2bf(float x) {
    union { float f; unsigned u; } v; v.f = x;
    unsigned r = (v.u + 0x7FFF + ((v.u >> 16) & 1)) >> 16;
    return (ushort)r;
}

// ---------------- zero ints ----------------
__global__ void zero_int_kernel(int* __restrict__ p, int n) {
    int i = blockIdx.x * blockDim.x + threadIdx.x;
    if (i < n) p[i] = 0;
}

// ---------------- fp32 -> bf16 convert ----------------
__global__ void cvt_kernel(const float4* __restrict__ in, ushort4* __restrict__ out, int n4) {
    int i = blockIdx.x * blockDim.x + threadIdx.x;
    if (i < n4) {
        float4 v = in[i];
        out[i] = make_ushort4(f2bf(v.x), f2bf(v.y), f2bf(v.z), f2bf(v.w));
    }
}

// ---------------- degree histogram ----------------
__global__ void hist_kernel(const int* __restrict__ dst, int E, int* __restrict__ deg) {
    int t = blockIdx.x * blockDim.x + threadIdx.x;
    if (t < E) atomicAdd(&deg[dst[t]], 1);
}

// ---------------- single-block exclusive scan ----------------
__global__ __launch_bounds__(1024) void scan_kernel(const int* __restrict__ deg, int n,
                                                    int* __restrict__ rp) {
    __shared__ int sums[1024];
    const int tid = threadIdx.x;
    const int chunk = (n + 1023) / 1024;
    const int s0 = tid * chunk, s1 = min(s0 + chunk, n);
    int s = 0;
    for (int i = s0; i < s1; i++) s += deg[i];
    sums[tid] = s;
    __syncthreads();
    for (int off = 1; off < 1024; off <<= 1) {
        int v = (tid >= off) ? sums[tid - off] : 0;
        __syncthreads();
        sums[tid] += v;
        __syncthreads();
    }
    int base = (tid > 0) ? sums[tid - 1] : 0;
    for (int i = s0; i < s1; i++) { rp[i] = base; base += deg[i]; }
    if (tid == 1023) rp[n] = sums[1023];
}

// ---------------- CSR fill ----------------
__global__ void fill_kernel(const int* __restrict__ src, const int* __restrict__ dst, int E,
                            const int* __restrict__ rp, int* __restrict__ cur,
                            int* __restrict__ csr_src) {
    int t = blockIdx.x * blockDim.x + threadIdx.x;
    if (t >= E) return;
    int d = dst[t];
    int pos = atomicAdd(&cur[d], 1);
    csr_src[rp[d] + pos] = src[t];
}

// ---------------- cnt from rowptr ----------------
__global__ void cnt_kernel(const int* __restrict__ rp, int n, float* __restrict__ cnt) {
    int i = blockIdx.x * blockDim.x + threadIdx.x;
    if (i < n) cnt[i] = (float)(rp[i + 1] - rp[i]);
}

// ---------------- pull gather: acc[r] = sum X[csr_src[e]] ----------------
template <int D>
__global__ __launch_bounds__(256) void gather_kernel(const int* __restrict__ rp,
                                                     const int* __restrict__ csr_src,
                                                     const float* __restrict__ X,
                                                     float* __restrict__ acc, int n) {
    constexpr int LPR = D / 4;
    constexpr int RPB = 256 / LPR;
    const int tid = threadIdx.x;
    const int r = blockIdx.x * RPB + tid / LPR;
    const int lane = tid % LPR;
    if (r >= n) return;
    const int e0 = rp[r], e1 = rp[r + 1];
    float4 s = make_float4(0.f, 0.f, 0.f, 0.f);
    for (int e = e0; e < e1; e++) {
        const int sidx = csr_src[e];
        float4 v = ((const float4*)(X + (long)sidx * D))[lane];
        s.x += v.x; s.y += v.y; s.z += v.z; s.w += v.w;
    }
    ((float4*)(acc + (long)r * D))[lane] = s;
}

// ---------------- fp32 vector GEMM (small M paths) ----------------
template <bool DUAL, bool SCALE0, bool HAS_BIAS, bool RELU, bool OUT_BF16>
__global__ __launch_bounds__(256) void gemm_kernel(
    int M, int K0, int K1,
    const float* __restrict__ A0, const float* __restrict__ A1,
    const float* __restrict__ W0, const float* __restrict__ W1,
    const float* __restrict__ bias,
    const float* __restrict__ cnt,
    void* __restrict__ Cout) {
    __shared__ float As[8][132];
    __shared__ float Ws[8][132];
    const int tid = threadIdx.x;
    const int row0 = blockIdx.x * 128, col0 = blockIdx.y * 128;
    const int ty = tid >> 4, tx = tid & 15;
    const int lrow = tid >> 1;
    const int lc4 = (tid & 1) * 4;

    float c[8][8];
#pragma unroll
    for (int i = 0; i < 8; i++)
#pragma unroll
        for (int j = 0; j < 8; j++) c[i][j] = 0.f;

    const int arow = row0 + lrow;
    const int wn = col0 + lrow;
    float scale0 = 1.f;
    if (SCALE0) {
        float cv = (arow < M) ? cnt[arow] : 1.f;
        scale0 = 1.f / fmaxf(cv, 1.f);
    }

    const int KT = K0 + (DUAL ? K1 : 0);
    for (int k0 = 0; k0 < KT; k0 += 8) {
        const int k = k0 + lc4;
        float4 av = make_float4(0.f, 0.f, 0.f, 0.f);
        if (arow < M) {
            if (!DUAL || k < K0) {
                av = *(const float4*)(A0 + (long)arow * K0 + k);
                if (SCALE0) { av.x *= scale0; av.y *= scale0; av.z *= scale0; av.w *= scale0; }
            } else {
                av = *(const float4*)(A1 + (long)arow * K1 + (k - K0));
            }
        }
        float4 wv;
        if (!DUAL || k < K0) wv = *(const float4*)(W0 + (long)wn * K0 + k);
        else                 wv = *(const float4*)(W1 + (long)wn * K1 + (k - K0));

        __syncthreads();
        As[lc4 + 0][lrow] = av.x; As[lc4 + 1][lrow] = av.y;
        As[lc4 + 2][lrow] = av.z; As[lc4 + 3][lrow] = av.w;
        Ws[lc4 + 0][lrow] = wv.x; Ws[lc4 + 1][lrow] = wv.y;
        Ws[lc4 + 2][lrow] = wv.z; Ws[lc4 + 3][lrow] = wv.w;
        __syncthreads();

#pragma unroll
        for (int kk = 0; kk < 8; kk++) {
            float a[8], b[8];
#pragma unroll
            for (int i = 0; i < 8; i++) a[i] = As[kk][ty * 8 + i];
#pragma unroll
            for (int j = 0; j < 8; j++) b[j] = Ws[kk][tx * 8 + j];
#pragma unroll
            for (int i = 0; i < 8; i++)
#pragma unroll
                for (int j = 0; j < 8; j++) c[i][j] += a[i] * b[j];
        }
    }

#pragma unroll
    for (int i = 0; i < 8; i++) {
        int row = row0 + ty * 8 + i;
        if (row >= M) break;
        float tmp[8];
#pragma unroll
        for (int j = 0; j < 8; j++) {
            int col = col0 + tx * 8 + j;
            float v = c[i][j];
            if (HAS_BIAS) v += bias[col];
            if (RELU) v = fmaxf(v, 0.f);
            tmp[j] = v;
        }
        if constexpr (OUT_BF16) {
            ushort* cp = (ushort*)Cout + (size_t)row * 256 + col0 + tx * 8;
            *(ushort4*)cp = make_ushort4(f2bf(tmp[0]), f2bf(tmp[1]), f2bf(tmp[2]), f2bf(tmp[3]));
            *(ushort4*)(cp + 4) = make_ushort4(f2bf(tmp[4]), f2bf(tmp[5]), f2bf(tmp[6]), f2bf(tmp[7]));
        } else {
            float* cp = (float*)Cout + (size_t)row * 256 + col0 + tx * 8;
            *(float4*)(cp) = make_float4(tmp[0], tmp[1], tmp[2], tmp[3]);
            *(float4*)(cp + 4) = make_float4(tmp[4], tmp[5], tmp[6], tmp[7]);
        }
    }
}

// ---------------- bf16 MFMA GEMM: Cb[M,256] = relu(A@W^T + bias + accp/cnt) ----------------
// 128x128 tile, 4 waves (2x2), each wave 4x4 tiles of 16x16x32 MFMA.
template <int K>
__global__ __launch_bounds__(256, 2) void mfma_gemm_kernel(
    int M, const ushort* __restrict__ A, const ushort* __restrict__ W,
    const float* __restrict__ bias, const float* __restrict__ cnt,
    const float* __restrict__ accp, ushort* __restrict__ Cb) {
    constexpr int RS = 40;  // LDS row stride (ushorts), 16B-aligned, spreads banks
    __shared__ ushort Als[128 * RS];
    __shared__ ushort Wls[128 * RS];
    const int tid = threadIdx.x;
    const int m0 = blockIdx.x * 128, n0 = blockIdx.y * 128;
    const int lane = tid & 63, w = tid >> 6;
    const int wm = w >> 1, wn = w & 1;
    const int m16 = lane & 15, q = lane >> 4;

    f32x4 acc[4][4] = {};

    for (int k0 = 0; k0 < K; k0 += 32) {
        bf16x8 a_st[2], w_st[2];
#pragma unroll
        for (int r = 0; r < 2; r++) {
            int chunk = tid + r * 256;        // 512 chunks of 16B per 8KB tile
            int row = chunk >> 2, off = (chunk & 3) * 8;
            int ga = min(m0 + row, M - 1);
            a_st[r] = *(const bf16x8*)(A + (size_t)ga * K + k0 + off);
            w_st[r] = *(const bf16x8*)(W + (size_t)(n0 + row) * K + k0 + off);
        }
        __syncthreads();
#pragma unroll
        for (int r = 0; r < 2; r++) {
            int chunk = tid + r * 256;
            int row = chunk >> 2, off = (chunk & 3) * 8;
            *(bf16x8*)(&Als[row * RS + off]) = a_st[r];
            *(bf16x8*)(&Wls[row * RS + off]) = w_st[r];
        }
        __syncthreads();
        bf16x8 af[4], bf[4];
#pragma unroll
        for (int t = 0; t < 4; t++) {
            af[t] = *(const bf16x8*)(&Als[(wm * 64 + t * 16 + m16) * RS + q * 8]);
            bf[t] = *(const bf16x8*)(&Wls[(wn * 64 + t * 16 + m16) * RS + q * 8]);
        }
#pragma unroll
        for (int mt = 0; mt < 4; mt++)
#pragma unroll
            for (int nt = 0; nt < 4; nt++)
                acc[mt][nt] = __builtin_amdgcn_mfma_f32_16x16x32_bf16(af[mt], bf[nt], acc[mt][nt], 0, 0, 0);
    }

#pragma unroll
    for (int mt = 0; mt < 4; mt++) {
#pragma unroll
        for (int i = 0; i < 4; i++) {
            int row = m0 + wm * 64 + mt * 16 + q * 4 + i;
            if (row >= M) continue;
            float es = 1.f / fmaxf(cnt[row], 1.f);
#pragma unroll
            for (int nt = 0; nt < 4; nt++) {
                int col = n0 + wn * 64 + nt * 16 + m16;
                float v = acc[mt][nt][i] + bias[col] + accp[(size_t)row * 256 + col] * es;
                Cb[(size_t)row * 256 + col] = f2bf(fmaxf(v, 0.f));
            }
        }
    }
}

// ---------------- fused head: gather bf16 rows -> MFMA(768->256) -> relu -> dot W2 ----------------
// 64 rows x 256 cols per block; wave w owns cols [w*64, w*64+64).
__global__ __launch_bounds__(256, 2) void mfma_head_kernel(
    const ushort* __restrict__ hp, const ushort* __restrict__ hm, const ushort* __restrict__ ht,
    const int* __restrict__ pp, const int* __restrict__ pm, const int* __restrict__ pt,
    const ushort* __restrict__ W1, const float* __restrict__ b1,
    const float* __restrict__ W2, const float* __restrict__ b2,
    float* __restrict__ out) {
    constexpr int RS = 40;
    __shared__ ushort Als[64 * RS];
    __shared__ ushort Wls[256 * RS];
    __shared__ int pidx[3][64];
    __shared__ float b1s[256], W2s[256];
    __shared__ float partial[64][65];

    const int tid = threadIdx.x;
    const int row0 = blockIdx.x * 64;
    if (tid < 64) {
        int i = row0 + tid, ii = (i < BB) ? i : 0;
        pidx[0][tid] = pp[ii]; pidx[1][tid] = pm[ii]; pidx[2][tid] = pt[ii];
    }
    b1s[tid] = b1[tid];
    W2s[tid] = W2[tid];
    __syncthreads();

    const int lane = tid & 63, w = tid >> 6;
    const int m16 = lane & 15, q = lane >> 4;
    const int arow = tid >> 2, aoff = (tid & 3) * 8;

    f32x4 acc[4][4] = {};

    for (int k0 = 0; k0 < 768; k0 += 32) {
        const int seg = k0 >> 8, ko = k0 & 255;
        const ushort* T = (seg == 0) ? hp : (seg == 1) ? hm : ht;
        const int ridx = pidx[seg][arow];
        bf16x8 a_st = *(const bf16x8*)(T + (size_t)ridx * 256 + ko + aoff);
        bf16x8 w_st[4];
#pragma unroll
        for (int r = 0; r < 4; r++) {
            int chunk = tid + r * 256;        // 1024 chunks for 256x32 W tile
            int row = chunk >> 2, off = (chunk & 3) * 8;
            w_st[r] = *(const bf16x8*)(W1 + (size_t)row * 768 + k0 + off);
        }
        __syncthreads();
        *(bf16x8*)(&Als[arow * RS + aoff]) = a_st;
#pragma unroll
        for (int r = 0; r < 4; r++) {
            int chunk = tid + r * 256;
            int row = chunk >> 2, off = (chunk & 3) * 8;
            *(bf16x8*)(&Wls[row * RS + off]) = w_st[r];
        }
        __syncthreads();
        bf16x8 af[4], bfr[4];
#pragma unroll
        for (int t = 0; t < 4; t++) {
            af[t] = *(const bf16x8*)(&Als[(t * 16 + m16) * RS + q * 8]);
            bfr[t] = *(const bf16x8*)(&Wls[(w * 64 + t * 16 + m16) * RS + q * 8]);
        }
#pragma unroll
        for (int mt = 0; mt < 4; mt++)
#pragma unroll
            for (int nt = 0; nt < 4; nt++)
                acc[mt][nt] = __builtin_amdgcn_mfma_f32_16x16x32_bf16(af[mt], bfr[nt], acc[mt][nt], 0, 0, 0);
    }

#pragma unroll
    for (int mt = 0; mt < 4; mt++) {
#pragma unroll
        for (int i = 0; i < 4; i++) {
            int rloc = mt * 16 + q * 4 + i;
            float p = 0.f;
#pragma unroll
            for (int nt = 0; nt < 4; nt++) {
                int col = w * 64 + nt * 16 + m16;
                float h = acc[mt][nt][i] + b1s[col];
                h = fmaxf(h, 0.f);
                p += h * W2s[col];
            }
            partial[rloc][(w << 4) | m16] = p;
        }
    }
    __syncthreads();
    if (tid < 64) {
        float s = 0.f;
#pragma unroll
        for (int j = 0; j < 64; j++) s += partial[tid][j];
        int r = row0 + tid;
        if (r < BB) out[r] = s + b2[0];
    }
}

// ---------------- launch ----------------
extern "C" void kernel_launch(void* const* d_in, const int* in_sizes, int n_in,
                              void* d_out, int out_size, void* d_ws, size_t ws_size,
                              hipStream_t stream) {
    const float* emb_pep = (const float*)d_in[0];
    const float* emb_mhc = (const float*)d_in[1];
    const float* emb_tcr = (const float*)d_in[2];
    const int* src_pm = (const int*)d_in[3];
    const int* dst_pm = (const int*)d_in[4];
    const int* src_mt = (const int*)d_in[5];
    const int* dst_mt = (const int*)d_in[6];
    const int* pack_pep = (const int*)d_in[7];
    const int* pack_mhc = (const int*)d_in[8];
    const int* pack_tcr = (const int*)d_in[9];
    const float* l1_pm_Wl = (const float*)d_in[10];
    const float* l1_pm_bl = (const float*)d_in[11];
    const float* l1_pm_Wr = (const float*)d_in[12];
    const float* l1_mt_Wl = (const float*)d_in[13];
    const float* l1_mt_bl = (const float*)d_in[14];
    const float* l1_mt_Wr = (const float*)d_in[15];
    const float* l2_pm_Wl = (const float*)d_in[16];
    const float* l2_pm_bl = (const float*)d_in[17];
    const float* l2_pm_Wr = (const float*)d_in[18];
    const float* l2_mt_Wl = (const float*)d_in[19];
    const float* l2_mt_bl = (const float*)d_in[20];
    const float* l2_mt_Wr = (const float*)d_in[21];
    const float* proj_W = (const float*)d_in[22];
    const float* proj_b = (const float*)d_in[23];
    const float* head_W1 = (const float*)d_in[24];
    const float* head_b1 = (const float*)d_in[25];
    const float* head_W2 = (const float*)d_in[26];
    const float* head_b2 = (const float*)d_in[27];
    float* out = (float*)d_out;

    // ---------------- workspace layout ----------------
    int* ib = (int*)d_ws;
    int* deg_pm = ib;                 // 5000
    int* cur_pm = ib + 5000;          // 5000
    int* deg_mt = ib + 10000;         // 100000
    int* cur_mt = ib + 110000;        // 100000   [zero region: first 210000 ints]
    int* rp_pm  = ib + 210000;        // 5001 (pad 5008)
    int* rp_mt  = ib + 215008;        // 100001 (pad 100008)
    int* csr_pm = ib + 315016;        // 200000
    int* csr_mt = ib + 515016;        // 400000 -> ints end at 915016 (3,660,064 B)

    float* f = (float*)(ib + 915016);
    float* cnt_pm = f;                // 5000
    float* cnt_mt = f + 5000;         // 100000
    float* agg_pm = f + 105000;       // 640000
    float* Z      = f + 745000;       // 1280000 (Z1 then Z2)
    float* mhc1   = f + 2025000;      // 1280000 (fp32, feeds Z2 & mhc2)
    float* acc    = f + 3305000;      // 25600000 (tcr1_acc then tcr2_acc)
    // floats end at f + 28905000

    ushort* u = (ushort*)(f + 28905000);
    ushort* Wr1_b   = u;              // 32768   (l1_mt_Wr)
    ushort* Wr2_b   = u + 32768;      // 65536   (l2_mt_Wr)
    ushort* W1_b    = u + 98304;      // 196608  (head_W1)
    ushort* hp_b    = u + 294912;     // 5120000
    ushort* mhc2_b  = u + 5414912;    // 1280000
    ushort* tcr1_b  = u + 6694912;    // 25600000
    ushort* ushare  = u + 32294912;   // 25600000 (emb_tcr_b first 12.8M, then tcr2_b whole)
    ushort* emb_tcr_b = ushare;
    ushort* tcr2_b    = ushare;       // written after emb_tcr_b is dead
    // total ~235 MB

    // ---------------- CSR build ----------------
    zero_int_kernel<<<(210000 + 255) / 256, 256, 0, stream>>>(ib, 210000);
    hist_kernel<<<(EPM + 255) / 256, 256, 0, stream>>>(dst_pm, EPM, deg_pm);
    hist_kernel<<<(EMT + 255) / 256, 256, 0, stream>>>(dst_mt, EMT, deg_mt);
    scan_kernel<<<1, 1024, 0, stream>>>(deg_pm, NMHC, rp_pm);
    scan_kernel<<<1, 1024, 0, stream>>>(deg_mt, NTCR, rp_mt);
    fill_kernel<<<(EPM + 255) / 256, 256, 0, stream>>>(src_pm, dst_pm, EPM, rp_pm, cur_pm, csr_pm);
    fill_kernel<<<(EMT + 255) / 256, 256, 0, stream>>>(src_mt, dst_mt, EMT, rp_mt, cur_mt, csr_mt);
    cnt_kernel<<<(NMHC + 255) / 256, 256, 0, stream>>>(rp_pm, NMHC, cnt_pm);
    cnt_kernel<<<(NTCR + 255) / 256, 256, 0, stream>>>(rp_mt, NTCR, cnt_mt);

    // ---------------- bf16 conversions ----------------
    cvt_kernel<<<(3200000 + 255) / 256, 256, 0, stream>>>((const float4*)emb_tcr, (ushort4*)emb_tcr_b, 3200000);
    cvt_kernel<<<(8192 + 255) / 256, 256, 0, stream>>>((const float4*)l1_mt_Wr, (ushort4*)Wr1_b, 8192);
    cvt_kernel<<<(16384 + 255) / 256, 256, 0, stream>>>((const float4*)l2_mt_Wr, (ushort4*)Wr2_b, 16384);
    cvt_kernel<<<(49152 + 255) / 256, 256, 0, stream>>>((const float4*)head_W1, (ushort4*)W1_b, 49152);

    // ---------------- pipeline ----------------
    dim3 g5((NMHC + 127) / 128, 2), g20((NPEP + 127) / 128, 2);
    dim3 gt((NTCR + 127) / 128, 2);

    gather_kernel<128><<<(NMHC + 7) / 8, 256, 0, stream>>>(rp_pm, csr_pm, emb_pep, agg_pm, NMHC);

    // mhc1 = relu( mean_pm @ l1_pm_Wl^T + bl + emb_mhc @ l1_pm_Wr^T )   [fp32]
    gemm_kernel<true, true, true, true, false><<<g5, 256, 0, stream>>>(
        NMHC, 128, 128, agg_pm, emb_mhc, l1_pm_Wl, l1_pm_Wr, l1_pm_bl, cnt_pm, mhc1);
    // Z = emb_mhc @ l1_mt_Wl^T   [fp32]
    gemm_kernel<false, false, false, false, false><<<g5, 256, 0, stream>>>(
        NMHC, 128, 0, emb_mhc, nullptr, l1_mt_Wl, nullptr, nullptr, nullptr, Z);
    // acc = segsum(Z[src_mt] -> dst_mt)
    gather_kernel<256><<<(NTCR + 3) / 4, 256, 0, stream>>>(rp_mt, csr_mt, Z, acc, NTCR);
    // tcr1_b = relu( emb_tcr_b @ Wr1_b^T + bl + acc/cnt )   [MFMA]
    mfma_gemm_kernel<128><<<gt, 256, 0, stream>>>(NTCR, emb_tcr_b, Wr1_b, l1_mt_bl, cnt_mt, acc, tcr1_b);

    // mhc2 = relu( mean_pm @ l2_pm_Wl^T + bl + mhc1 @ l2_pm_Wr^T )  -> bf16
    gemm_kernel<true, true, true, true, true><<<g5, 256, 0, stream>>>(
        NMHC, 128, 256, agg_pm, mhc1, l2_pm_Wl, l2_pm_Wr, l2_pm_bl, cnt_pm, mhc2_b);
    // Z = mhc1 @ l2_mt_Wl^T   [fp32]
    gemm_kernel<false, false, false, false, false><<<g5, 256, 0, stream>>>(
        NMHC, 256, 0, mhc1, nullptr, l2_mt_Wl, nullptr, nullptr, nullptr, Z);
    // acc = segsum(Z[src_mt] -> dst_mt)   (tcr1 GEMM already consumed previous acc)
    gather_kernel<256><<<(NTCR + 3) / 4, 256, 0, stream>>>(rp_mt, csr_mt, Z, acc, NTCR);
    // tcr2_b = relu( tcr1_b @ Wr2_b^T + bl + acc/cnt )   [MFMA]  (emb_tcr_b now dead)
    mfma_gemm_kernel<256><<<gt, 256, 0, stream>>>(NTCR, tcr1_b, Wr2_b, l2_mt_bl, cnt_mt, acc, tcr2_b);

    // hp_b = emb_pep @ proj_W^T + proj_b  -> bf16 (no relu)
    gemm_kernel<false, false, true, false, true><<<g20, 256, 0, stream>>>(
        NPEP, 128, 0, emb_pep, nullptr, proj_W, nullptr, proj_b, nullptr, hp_b);

    // head
    mfma_head_kernel<<<(BB + 63) / 64, 256, 0, stream>>>(
        hp_b, mhc2_b, tcr2_b, pack_pep, pack_mhc, pack_tcr, W1_b, head_b1, head_W2, head_b2, out);
}

// Round 4
// 707.996 us; speedup vs baseline: 6.0602x; 1.2113x over previous
//
#include <hip/hip_runtime.h>

// ---------------- problem constants ----------------
constexpr int NPEP = 20000, NMHC = 5000, NTCR = 100000;
constexpr int EPM = 200000, EMT = 400000, BB = 50000;

typedef __attribute__((ext_vector_type(8))) short bf16x8;
typedef __attribute__((ext_vector_type(4))) float f32x4;

__device__ inline ushort f2bf(float x) {
    union { float f; unsigned u; } v; v.f = x;
    unsigned r = (v.u + 0x7FFF + ((v.u >> 16) & 1)) >> 16;
    return (ushort)r;
}

// ---------------- zero ints ----------------
__global__ void zero_int_kernel(int* __restrict__ p, int n) {
    int i = blockIdx.x * blockDim.x + threadIdx.x;
    if (i < n) p[i] = 0;
}

// ---------------- fp32 -> bf16 convert ----------------
__global__ void cvt_kernel(const float4* __restrict__ in, ushort4* __restrict__ out, int n4) {
    int i = blockIdx.x * blockDim.x + threadIdx.x;
    if (i < n4) {
        float4 v = in[i];
        out[i] = make_ushort4(f2bf(v.x), f2bf(v.y), f2bf(v.z), f2bf(v.w));
    }
}

// ---------------- degree histogram ----------------
__global__ void hist_kernel(const int* __restrict__ dst, int E, int* __restrict__ deg) {
    int t = blockIdx.x * blockDim.x + threadIdx.x;
    if (t < E) atomicAdd(&deg[dst[t]], 1);
}

// ---------------- 3-phase device-wide exclusive scan ----------------
// phase 1: per-block (1024-elem chunk) sums
__global__ __launch_bounds__(256) void blocksum_kernel(const int* __restrict__ deg, int n,
                                                       int* __restrict__ bsum) {
    __shared__ int red[256];
    const int tid = threadIdx.x;
    const int base = blockIdx.x * 1024;
    int s = 0;
#pragma unroll
    for (int j = 0; j < 4; j++) {
        int i = base + tid + j * 256;
        if (i < n) s += deg[i];
    }
    red[tid] = s;
    __syncthreads();
    for (int off = 128; off > 0; off >>= 1) {
        if (tid < off) red[tid] += red[tid + off];
        __syncthreads();
    }
    if (tid == 0) bsum[blockIdx.x] = red[0];
}

// phase 2: exclusive scan of <=128 block sums (in place), bsum[nb] = total
__global__ __launch_bounds__(128) void scanb_kernel(int* __restrict__ bsum, int nb) {
    __shared__ int s[128];
    const int tid = threadIdx.x;
    int v = (tid < nb) ? bsum[tid] : 0;
    s[tid] = v;
    __syncthreads();
    for (int off = 1; off < 128; off <<= 1) {
        int t = (tid >= off) ? s[tid - off] : 0;
        __syncthreads();
        s[tid] += t;
        __syncthreads();
    }
    if (tid < nb) bsum[tid] = (tid > 0) ? s[tid - 1] : 0;
    if (tid == 0) bsum[nb] = s[nb - 1];
}

// phase 3: emit rp (exclusive) + cnt (deg as float)
__global__ __launch_bounds__(256) void emit_kernel(const int* __restrict__ deg, int n,
                                                   const int* __restrict__ bsum, int nb,
                                                   int* __restrict__ rp, float* __restrict__ cnt) {
    __shared__ int tsum[256];
    const int tid = threadIdx.x;
    const int base = blockIdx.x * 1024;
    const int i0 = base + tid * 4;
    int4 v = make_int4(0, 0, 0, 0);
    if (i0 + 3 < n) v = *(const int4*)(deg + i0);
    else if (i0 < n) {
        int t[4] = {0, 0, 0, 0};
        for (int j = 0; j < 4 && i0 + j < n; j++) t[j] = deg[i0 + j];
        v = make_int4(t[0], t[1], t[2], t[3]);
    }
    int s = v.x + v.y + v.z + v.w;
    tsum[tid] = s;
    __syncthreads();
    for (int off = 1; off < 256; off <<= 1) {
        int t = (tid >= off) ? tsum[tid - off] : 0;
        __syncthreads();
        tsum[tid] += t;
        __syncthreads();
    }
    int ex = ((tid > 0) ? tsum[tid - 1] : 0) + bsum[blockIdx.x];
    if (i0 + 3 < n) {
        int r1 = ex + v.x, r2 = r1 + v.y, r3 = r2 + v.z;
        *(int4*)(rp + i0) = make_int4(ex, r1, r2, r3);
        *(float4*)(cnt + i0) = make_float4((float)v.x, (float)v.y, (float)v.z, (float)v.w);
    } else if (i0 < n) {
        int r = ex;
        int vv[4] = {v.x, v.y, v.z, v.w};
        for (int j = 0; j < 4 && i0 + j < n; j++) {
            rp[i0 + j] = r;
            cnt[i0 + j] = (float)vv[j];
            r += vv[j];
        }
    }
    if (blockIdx.x == 0 && tid == 0) rp[n] = bsum[nb];
}

// ---------------- CSR fill ----------------
__global__ void fill_kernel(const int* __restrict__ src, const int* __restrict__ dst, int E,
                            const int* __restrict__ rp, int* __restrict__ cur,
                            int* __restrict__ csr_src) {
    int t = blockIdx.x * blockDim.x + threadIdx.x;
    if (t >= E) return;
    int d = dst[t];
    int pos = atomicAdd(&cur[d], 1);
    csr_src[rp[d] + pos] = src[t];
}

// ---------------- pull gather: acc[r] = sum X[csr_src[e]] ----------------
template <int D>
__global__ __launch_bounds__(256) void gather_kernel(const int* __restrict__ rp,
                                                     const int* __restrict__ csr_src,
                                                     const float* __restrict__ X,
                                                     float* __restrict__ acc, int n) {
    constexpr int LPR = D / 4;
    constexpr int RPB = 256 / LPR;
    const int tid = threadIdx.x;
    const int r = blockIdx.x * RPB + tid / LPR;
    const int lane = tid % LPR;
    if (r >= n) return;
    const int e0 = rp[r], e1 = rp[r + 1];
    float4 s = make_float4(0.f, 0.f, 0.f, 0.f);
    for (int e = e0; e < e1; e++) {
        const int sidx = csr_src[e];
        float4 v = ((const float4*)(X + (long)sidx * D))[lane];
        s.x += v.x; s.y += v.y; s.z += v.z; s.w += v.w;
    }
    ((float4*)(acc + (long)r * D))[lane] = s;
}

// ---------------- fp32 vector GEMM (small M paths) ----------------
template <bool DUAL, bool SCALE0, bool HAS_BIAS, bool RELU, bool OUT_BF16>
__global__ __launch_bounds__(256) void gemm_kernel(
    int M, int K0, int K1,
    const float* __restrict__ A0, const float* __restrict__ A1,
    const float* __restrict__ W0, const float* __restrict__ W1,
    const float* __restrict__ bias,
    const float* __restrict__ cnt,
    void* __restrict__ Cout) {
    __shared__ float As[8][132];
    __shared__ float Ws[8][132];
    const int tid = threadIdx.x;
    const int row0 = blockIdx.x * 128, col0 = blockIdx.y * 128;
    const int ty = tid >> 4, tx = tid & 15;
    const int lrow = tid >> 1;
    const int lc4 = (tid & 1) * 4;

    float c[8][8];
#pragma unroll
    for (int i = 0; i < 8; i++)
#pragma unroll
        for (int j = 0; j < 8; j++) c[i][j] = 0.f;

    const int arow = row0 + lrow;
    const int wn = col0 + lrow;
    float scale0 = 1.f;
    if (SCALE0) {
        float cv = (arow < M) ? cnt[arow] : 1.f;
        scale0 = 1.f / fmaxf(cv, 1.f);
    }

    const int KT = K0 + (DUAL ? K1 : 0);
    for (int k0 = 0; k0 < KT; k0 += 8) {
        const int k = k0 + lc4;
        float4 av = make_float4(0.f, 0.f, 0.f, 0.f);
        if (arow < M) {
            if (!DUAL || k < K0) {
                av = *(const float4*)(A0 + (long)arow * K0 + k);
                if (SCALE0) { av.x *= scale0; av.y *= scale0; av.z *= scale0; av.w *= scale0; }
            } else {
                av = *(const float4*)(A1 + (long)arow * K1 + (k - K0));
            }
        }
        float4 wv;
        if (!DUAL || k < K0) wv = *(const float4*)(W0 + (long)wn * K0 + k);
        else                 wv = *(const float4*)(W1 + (long)wn * K1 + (k - K0));

        __syncthreads();
        As[lc4 + 0][lrow] = av.x; As[lc4 + 1][lrow] = av.y;
        As[lc4 + 2][lrow] = av.z; As[lc4 + 3][lrow] = av.w;
        Ws[lc4 + 0][lrow] = wv.x; Ws[lc4 + 1][lrow] = wv.y;
        Ws[lc4 + 2][lrow] = wv.z; Ws[lc4 + 3][lrow] = wv.w;
        __syncthreads();

#pragma unroll
        for (int kk = 0; kk < 8; kk++) {
            float a[8], b[8];
#pragma unroll
            for (int i = 0; i < 8; i++) a[i] = As[kk][ty * 8 + i];
#pragma unroll
            for (int j = 0; j < 8; j++) b[j] = Ws[kk][tx * 8 + j];
#pragma unroll
            for (int i = 0; i < 8; i++)
#pragma unroll
                for (int j = 0; j < 8; j++) c[i][j] += a[i] * b[j];
        }
    }

#pragma unroll
    for (int i = 0; i < 8; i++) {
        int row = row0 + ty * 8 + i;
        if (row >= M) break;
        float tmp[8];
#pragma unroll
        for (int j = 0; j < 8; j++) {
            int col = col0 + tx * 8 + j;
            float v = c[i][j];
            if (HAS_BIAS) v += bias[col];
            if (RELU) v = fmaxf(v, 0.f);
            tmp[j] = v;
        }
        if constexpr (OUT_BF16) {
            ushort* cp = (ushort*)Cout + (size_t)row * 256 + col0 + tx * 8;
            *(ushort4*)cp = make_ushort4(f2bf(tmp[0]), f2bf(tmp[1]), f2bf(tmp[2]), f2bf(tmp[3]));
            *(ushort4*)(cp + 4) = make_ushort4(f2bf(tmp[4]), f2bf(tmp[5]), f2bf(tmp[6]), f2bf(tmp[7]));
        } else {
            float* cp = (float*)Cout + (size_t)row * 256 + col0 + tx * 8;
            *(float4*)(cp) = make_float4(tmp[0], tmp[1], tmp[2], tmp[3]);
            *(float4*)(cp + 4) = make_float4(tmp[4], tmp[5], tmp[6], tmp[7]);
        }
    }
}

// ---------------- bf16 MFMA GEMM: Cb[M,256] = relu(A@W^T + bias + accp/cnt) ----------------
template <int K>
__global__ __launch_bounds__(256, 2) void mfma_gemm_kernel(
    int M, const ushort* __restrict__ A, const ushort* __restrict__ W,
    const float* __restrict__ bias, const float* __restrict__ cnt,
    const float* __restrict__ accp, ushort* __restrict__ Cb) {
    constexpr int RS = 40;
    __shared__ ushort Als[128 * RS];
    __shared__ ushort Wls[128 * RS];
    const int tid = threadIdx.x;
    const int m0 = blockIdx.x * 128, n0 = blockIdx.y * 128;
    const int lane = tid & 63, w = tid >> 6;
    const int wm = w >> 1, wn = w & 1;
    const int m16 = lane & 15, q = lane >> 4;

    f32x4 acc[4][4] = {};

    for (int k0 = 0; k0 < K; k0 += 32) {
        bf16x8 a_st[2], w_st[2];
#pragma unroll
        for (int r = 0; r < 2; r++) {
            int chunk = tid + r * 256;
            int row = chunk >> 2, off = (chunk & 3) * 8;
            int ga = min(m0 + row, M - 1);
            a_st[r] = *(const bf16x8*)(A + (size_t)ga * K + k0 + off);
            w_st[r] = *(const bf16x8*)(W + (size_t)(n0 + row) * K + k0 + off);
        }
        __syncthreads();
#pragma unroll
        for (int r = 0; r < 2; r++) {
            int chunk = tid + r * 256;
            int row = chunk >> 2, off = (chunk & 3) * 8;
            *(bf16x8*)(&Als[row * RS + off]) = a_st[r];
            *(bf16x8*)(&Wls[row * RS + off]) = w_st[r];
        }
        __syncthreads();
        bf16x8 af[4], bf[4];
#pragma unroll
        for (int t = 0; t < 4; t++) {
            af[t] = *(const bf16x8*)(&Als[(wm * 64 + t * 16 + m16) * RS + q * 8]);
            bf[t] = *(const bf16x8*)(&Wls[(wn * 64 + t * 16 + m16) * RS + q * 8]);
        }
#pragma unroll
        for (int mt = 0; mt < 4; mt++)
#pragma unroll
            for (int nt = 0; nt < 4; nt++)
                acc[mt][nt] = __builtin_amdgcn_mfma_f32_16x16x32_bf16(af[mt], bf[nt], acc[mt][nt], 0, 0, 0);
    }

#pragma unroll
    for (int mt = 0; mt < 4; mt++) {
#pragma unroll
        for (int i = 0; i < 4; i++) {
            int row = m0 + wm * 64 + mt * 16 + q * 4 + i;
            if (row >= M) continue;
            float es = 1.f / fmaxf(cnt[row], 1.f);
#pragma unroll
            for (int nt = 0; nt < 4; nt++) {
                int col = n0 + wn * 64 + nt * 16 + m16;
                float v = acc[mt][nt][i] + bias[col] + accp[(size_t)row * 256 + col] * es;
                Cb[(size_t)row * 256 + col] = f2bf(fmaxf(v, 0.f));
            }
        }
    }
}

// ---------------- fused head ----------------
__global__ __launch_bounds__(256, 2) void mfma_head_kernel(
    const ushort* __restrict__ hp, const ushort* __restrict__ hm, const ushort* __restrict__ ht,
    const int* __restrict__ pp, const int* __restrict__ pm, const int* __restrict__ pt,
    const ushort* __restrict__ W1, const float* __restrict__ b1,
    const float* __restrict__ W2, const float* __restrict__ b2,
    float* __restrict__ out) {
    constexpr int RS = 40;
    __shared__ ushort Als[64 * RS];
    __shared__ ushort Wls[256 * RS];
    __shared__ int pidx[3][64];
    __shared__ float b1s[256], W2s[256];
    __shared__ float partial[64][65];

    const int tid = threadIdx.x;
    const int row0 = blockIdx.x * 64;
    if (tid < 64) {
        int i = row0 + tid, ii = (i < BB) ? i : 0;
        pidx[0][tid] = pp[ii]; pidx[1][tid] = pm[ii]; pidx[2][tid] = pt[ii];
    }
    b1s[tid] = b1[tid];
    W2s[tid] = W2[tid];
    __syncthreads();

    const int lane = tid & 63, w = tid >> 6;
    const int m16 = lane & 15, q = lane >> 4;
    const int arow = tid >> 2, aoff = (tid & 3) * 8;

    f32x4 acc[4][4] = {};

    for (int k0 = 0; k0 < 768; k0 += 32) {
        const int seg = k0 >> 8, ko = k0 & 255;
        const ushort* T = (seg == 0) ? hp : (seg == 1) ? hm : ht;
        const int ridx = pidx[seg][arow];
        bf16x8 a_st = *(const bf16x8*)(T + (size_t)ridx * 256 + ko + aoff);
        bf16x8 w_st[4];
#pragma unroll
        for (int r = 0; r < 4; r++) {
            int chunk = tid + r * 256;
            int row = chunk >> 2, off = (chunk & 3) * 8;
            w_st[r] = *(const bf16x8*)(W1 + (size_t)row * 768 + k0 + off);
        }
        __syncthreads();
        *(bf16x8*)(&Als[arow * RS + aoff]) = a_st;
#pragma unroll
        for (int r = 0; r < 4; r++) {
            int chunk = tid + r * 256;
            int row = chunk >> 2, off = (chunk & 3) * 8;
            *(bf16x8*)(&Wls[row * RS + off]) = w_st[r];
        }
        __syncthreads();
        bf16x8 af[4], bfr[4];
#pragma unroll
        for (int t = 0; t < 4; t++) {
            af[t] = *(const bf16x8*)(&Als[(t * 16 + m16) * RS + q * 8]);
            bfr[t] = *(const bf16x8*)(&Wls[(w * 64 + t * 16 + m16) * RS + q * 8]);
        }
#pragma unroll
        for (int mt = 0; mt < 4; mt++)
#pragma unroll
            for (int nt = 0; nt < 4; nt++)
                acc[mt][nt] = __builtin_amdgcn_mfma_f32_16x16x32_bf16(af[mt], bfr[nt], acc[mt][nt], 0, 0, 0);
    }

#pragma unroll
    for (int mt = 0; mt < 4; mt++) {
#pragma unroll
        for (int i = 0; i < 4; i++) {
            int rloc = mt * 16 + q * 4 + i;
            float p = 0.f;
#pragma unroll
            for (int nt = 0; nt < 4; nt++) {
                int col = w * 64 + nt * 16 + m16;
                float h = acc[mt][nt][i] + b1s[col];
                h = fmaxf(h, 0.f);
                p += h * W2s[col];
            }
            partial[rloc][(w << 4) | m16] = p;
        }
    }
    __syncthreads();
    if (tid < 64) {
        float s = 0.f;
#pragma unroll
        for (int j = 0; j < 64; j++) s += partial[tid][j];
        int r = row0 + tid;
        if (r < BB) out[r] = s + b2[0];
    }
}

// ---------------- launch ----------------
extern "C" void kernel_launch(void* const* d_in, const int* in_sizes, int n_in,
                              void* d_out, int out_size, void* d_ws, size_t ws_size,
                              hipStream_t stream) {
    const float* emb_pep = (const float*)d_in[0];
    const float* emb_mhc = (const float*)d_in[1];
    const float* emb_tcr = (const float*)d_in[2];
    const int* src_pm = (const int*)d_in[3];
    const int* dst_pm = (const int*)d_in[4];
    const int* src_mt = (const int*)d_in[5];
    const int* dst_mt = (const int*)d_in[6];
    const int* pack_pep = (const int*)d_in[7];
    const int* pack_mhc = (const int*)d_in[8];
    const int* pack_tcr = (const int*)d_in[9];
    const float* l1_pm_Wl = (const float*)d_in[10];
    const float* l1_pm_bl = (const float*)d_in[11];
    const float* l1_pm_Wr = (const float*)d_in[12];
    const float* l1_mt_Wl = (const float*)d_in[13];
    const float* l1_mt_bl = (const float*)d_in[14];
    const float* l1_mt_Wr = (const float*)d_in[15];
    const float* l2_pm_Wl = (const float*)d_in[16];
    const float* l2_pm_bl = (const float*)d_in[17];
    const float* l2_pm_Wr = (const float*)d_in[18];
    const float* l2_mt_Wl = (const float*)d_in[19];
    const float* l2_mt_bl = (const float*)d_in[20];
    const float* l2_mt_Wr = (const float*)d_in[21];
    const float* proj_W = (const float*)d_in[22];
    const float* proj_b = (const float*)d_in[23];
    const float* head_W1 = (const float*)d_in[24];
    const float* head_b1 = (const float*)d_in[25];
    const float* head_W2 = (const float*)d_in[26];
    const float* head_b2 = (const float*)d_in[27];
    float* out = (float*)d_out;

    // ---------------- workspace layout ----------------
    int* ib = (int*)d_ws;
    int* deg_pm = ib;                 // 5000
    int* cur_pm = ib + 5000;          // 5000
    int* deg_mt = ib + 10000;         // 100000
    int* cur_mt = ib + 110000;        // 100000   [zero region: first 210000 ints]
    int* rp_pm  = ib + 210000;        // 5001 (pad 5008)
    int* rp_mt  = ib + 215008;        // 100001 (pad 100008)
    int* csr_pm = ib + 315016;        // 200000
    int* csr_mt = ib + 515016;        // 400000
    int* bsum_pm = ib + 915016;       // 160
    int* bsum_mt = ib + 915176;       // 160 -> ints end at 915336

    float* f = (float*)(ib + 915336);
    float* cnt_pm = f;                // 5000
    float* cnt_mt = f + 5000;         // 100000
    float* agg_pm = f + 105000;       // 640000
    float* Z      = f + 745000;       // 1280000 (Z1 then Z2)
    float* mhc1   = f + 2025000;      // 1280000
    float* acc    = f + 3305000;      // 25600000
    // floats end at f + 28905000

    ushort* u = (ushort*)(f + 28905000);
    ushort* Wr1_b   = u;              // 32768
    ushort* Wr2_b   = u + 32768;      // 65536
    ushort* W1_b    = u + 98304;      // 196608
    ushort* hp_b    = u + 294912;     // 5120000
    ushort* mhc2_b  = u + 5414912;    // 1280000
    ushort* tcr1_b  = u + 6694912;    // 25600000
    ushort* ushare  = u + 32294912;   // 25600000
    ushort* emb_tcr_b = ushare;
    ushort* tcr2_b    = ushare;

    // ---------------- CSR build ----------------
    zero_int_kernel<<<(210000 + 255) / 256, 256, 0, stream>>>(ib, 210000);
    hist_kernel<<<(EPM + 255) / 256, 256, 0, stream>>>(dst_pm, EPM, deg_pm);
    hist_kernel<<<(EMT + 255) / 256, 256, 0, stream>>>(dst_mt, EMT, deg_mt);
    const int nb_pm = (NMHC + 1023) / 1024;   // 5
    const int nb_mt = (NTCR + 1023) / 1024;   // 98
    blocksum_kernel<<<nb_pm, 256, 0, stream>>>(deg_pm, NMHC, bsum_pm);
    blocksum_kernel<<<nb_mt, 256, 0, stream>>>(deg_mt, NTCR, bsum_mt);
    scanb_kernel<<<1, 128, 0, stream>>>(bsum_pm, nb_pm);
    scanb_kernel<<<1, 128, 0, stream>>>(bsum_mt, nb_mt);
    emit_kernel<<<nb_pm, 256, 0, stream>>>(deg_pm, NMHC, bsum_pm, nb_pm, rp_pm, cnt_pm);
    emit_kernel<<<nb_mt, 256, 0, stream>>>(deg_mt, NTCR, bsum_mt, nb_mt, rp_mt, cnt_mt);
    fill_kernel<<<(EPM + 255) / 256, 256, 0, stream>>>(src_pm, dst_pm, EPM, rp_pm, cur_pm, csr_pm);
    fill_kernel<<<(EMT + 255) / 256, 256, 0, stream>>>(src_mt, dst_mt, EMT, rp_mt, cur_mt, csr_mt);

    // ---------------- bf16 conversions ----------------
    cvt_kernel<<<(3200000 + 255) / 256, 256, 0, stream>>>((const float4*)emb_tcr, (ushort4*)emb_tcr_b, 3200000);
    cvt_kernel<<<(8192 + 255) / 256, 256, 0, stream>>>((const float4*)l1_mt_Wr, (ushort4*)Wr1_b, 8192);
    cvt_kernel<<<(16384 + 255) / 256, 256, 0, stream>>>((const float4*)l2_mt_Wr, (ushort4*)Wr2_b, 16384);
    cvt_kernel<<<(49152 + 255) / 256, 256, 0, stream>>>((const float4*)head_W1, (ushort4*)W1_b, 49152);

    // ---------------- pipeline ----------------
    dim3 g5((NMHC + 127) / 128, 2), g20((NPEP + 127) / 128, 2);
    dim3 gt((NTCR + 127) / 128, 2);

    gather_kernel<128><<<(NMHC + 7) / 8, 256, 0, stream>>>(rp_pm, csr_pm, emb_pep, agg_pm, NMHC);

    // mhc1 = relu( mean_pm @ l1_pm_Wl^T + bl + emb_mhc @ l1_pm_Wr^T )   [fp32]
    gemm_kernel<true, true, true, true, false><<<g5, 256, 0, stream>>>(
        NMHC, 128, 128, agg_pm, emb_mhc, l1_pm_Wl, l1_pm_Wr, l1_pm_bl, cnt_pm, mhc1);
    // Z = emb_mhc @ l1_mt_Wl^T   [fp32]
    gemm_kernel<false, false, false, false, false><<<g5, 256, 0, stream>>>(
        NMHC, 128, 0, emb_mhc, nullptr, l1_mt_Wl, nullptr, nullptr, nullptr, Z);
    // acc = segsum(Z[src_mt] -> dst_mt)
    gather_kernel<256><<<(NTCR + 3) / 4, 256, 0, stream>>>(rp_mt, csr_mt, Z, acc, NTCR);
    // tcr1_b = relu( emb_tcr_b @ Wr1_b^T + bl + acc/cnt )   [MFMA]
    mfma_gemm_kernel<128><<<gt, 256, 0, stream>>>(NTCR, emb_tcr_b, Wr1_b, l1_mt_bl, cnt_mt, acc, tcr1_b);

    // mhc2 = relu( mean_pm @ l2_pm_Wl^T + bl + mhc1 @ l2_pm_Wr^T )  -> bf16
    gemm_kernel<true, true, true, true, true><<<g5, 256, 0, stream>>>(
        NMHC, 128, 256, agg_pm, mhc1, l2_pm_Wl, l2_pm_Wr, l2_pm_bl, cnt_pm, mhc2_b);
    // Z = mhc1 @ l2_mt_Wl^T   [fp32]
    gemm_kernel<false, false, false, false, false><<<g5, 256, 0, stream>>>(
        NMHC, 256, 0, mhc1, nullptr, l2_mt_Wl, nullptr, nullptr, nullptr, Z);
    // acc = segsum(Z[src_mt] -> dst_mt)
    gather_kernel<256><<<(NTCR + 3) / 4, 256, 0, stream>>>(rp_mt, csr_mt, Z, acc, NTCR);
    // tcr2_b = relu( tcr1_b @ Wr2_b^T + bl + acc/cnt )   [MFMA]
    mfma_gemm_kernel<256><<<gt, 256, 0, stream>>>(NTCR, tcr1_b, Wr2_b, l2_mt_bl, cnt_mt, acc, tcr2_b);

    // hp_b = emb_pep @ proj_W^T + proj_b  -> bf16 (no relu)
    gemm_kernel<false, false, true, false, true><<<g20, 256, 0, stream>>>(
        NPEP, 128, 0, emb_pep, nullptr, proj_W, nullptr, proj_b, nullptr, hp_b);

    // head
    mfma_head_kernel<<<(BB + 63) / 64, 256, 0, stream>>>(
        hp_b, mhc2_b, tcr2_b, pack_pep, pack_mhc, pack_tcr, W1_b, head_b1, head_W2, head_b2, out);
}

// Round 5
// 650.154 us; speedup vs baseline: 6.5993x; 1.0890x over previous
//
#include <hip/hip_runtime.h>

// ---------------- problem constants ----------------
constexpr int NPEP = 20000, NMHC = 5000, NTCR = 100000;
constexpr int EPM = 200000, EMT = 400000, BB = 50000;

typedef __attribute__((ext_vector_type(8))) short bf16x8;
typedef __attribute__((ext_vector_type(4))) float f32x4;

__device__ inline ushort f2bf(float x) {
    union { float f; unsigned u; } v; v.f = x;
    unsigned r = (v.u + 0x7FFF + ((v.u >> 16) & 1)) >> 16;
    return (ushort)r;
}

// ---------------- zero ints ----------------
__global__ void zero_int_kernel(int* __restrict__ p, int n) {
    int i = blockIdx.x * blockDim.x + threadIdx.x;
    if (i < n) p[i] = 0;
}

// ---------------- fp32 -> bf16 convert ----------------
__global__ void cvt_kernel(const float4* __restrict__ in, ushort4* __restrict__ out, int n4) {
    int i = blockIdx.x * blockDim.x + threadIdx.x;
    if (i < n4) {
        float4 v = in[i];
        out[i] = make_ushort4(f2bf(v.x), f2bf(v.y), f2bf(v.z), f2bf(v.w));
    }
}

// ---------------- build concatenated padded weight [512 x Ktot] ----------------
// rows 0..255:   [ Wpm_l (128) | Wpm_r (K1) ]
// rows 256..511: [ 0      (128) | Wmt_l (K1) ]
__global__ void wcat_kernel(const float* __restrict__ Wpm_l, const float* __restrict__ Wpm_r,
                            const float* __restrict__ Wmt_l, int K1, int Ktot,
                            float* __restrict__ out) {
    int idx = blockIdx.x * blockDim.x + threadIdx.x;
    int total = 512 * Ktot;
    if (idx >= total) return;
    int r = idx / Ktot, k = idx - r * Ktot;
    float v;
    if (r < 256) v = (k < 128) ? Wpm_l[r * 128 + k] : Wpm_r[r * K1 + (k - 128)];
    else         v = (k < 128) ? 0.f : Wmt_l[(r - 256) * K1 + (k - 128)];
    out[idx] = v;
}

// ---------------- degree histogram ----------------
__global__ void hist_kernel(const int* __restrict__ dst, int E, int* __restrict__ deg) {
    int t = blockIdx.x * blockDim.x + threadIdx.x;
    if (t < E) atomicAdd(&deg[dst[t]], 1);
}

// ---------------- 3-phase device-wide exclusive scan ----------------
__global__ __launch_bounds__(256) void blocksum_kernel(const int* __restrict__ deg, int n,
                                                       int* __restrict__ bsum) {
    __shared__ int red[256];
    const int tid = threadIdx.x;
    const int base = blockIdx.x * 1024;
    int s = 0;
#pragma unroll
    for (int j = 0; j < 4; j++) {
        int i = base + tid + j * 256;
        if (i < n) s += deg[i];
    }
    red[tid] = s;
    __syncthreads();
    for (int off = 128; off > 0; off >>= 1) {
        if (tid < off) red[tid] += red[tid + off];
        __syncthreads();
    }
    if (tid == 0) bsum[blockIdx.x] = red[0];
}

__global__ __launch_bounds__(128) void scanb_kernel(int* __restrict__ bsum, int nb) {
    __shared__ int s[128];
    const int tid = threadIdx.x;
    int v = (tid < nb) ? bsum[tid] : 0;
    s[tid] = v;
    __syncthreads();
    for (int off = 1; off < 128; off <<= 1) {
        int t = (tid >= off) ? s[tid - off] : 0;
        __syncthreads();
        s[tid] += t;
        __syncthreads();
    }
    if (tid < nb) bsum[tid] = (tid > 0) ? s[tid - 1] : 0;
    if (tid == 0) bsum[nb] = s[nb - 1];
}

__global__ __launch_bounds__(256) void emit_kernel(const int* __restrict__ deg, int n,
                                                   const int* __restrict__ bsum, int nb,
                                                   int* __restrict__ rp, float* __restrict__ cnt) {
    __shared__ int tsum[256];
    const int tid = threadIdx.x;
    const int base = blockIdx.x * 1024;
    const int i0 = base + tid * 4;
    int4 v = make_int4(0, 0, 0, 0);
    if (i0 + 3 < n) v = *(const int4*)(deg + i0);
    else if (i0 < n) {
        int t[4] = {0, 0, 0, 0};
        for (int j = 0; j < 4 && i0 + j < n; j++) t[j] = deg[i0 + j];
        v = make_int4(t[0], t[1], t[2], t[3]);
    }
    int s = v.x + v.y + v.z + v.w;
    tsum[tid] = s;
    __syncthreads();
    for (int off = 1; off < 256; off <<= 1) {
        int t = (tid >= off) ? tsum[tid - off] : 0;
        __syncthreads();
        tsum[tid] += t;
        __syncthreads();
    }
    int ex = ((tid > 0) ? tsum[tid - 1] : 0) + bsum[blockIdx.x];
    if (i0 + 3 < n) {
        int r1 = ex + v.x, r2 = r1 + v.y, r3 = r2 + v.z;
        *(int4*)(rp + i0) = make_int4(ex, r1, r2, r3);
        *(float4*)(cnt + i0) = make_float4((float)v.x, (float)v.y, (float)v.z, (float)v.w);
    } else if (i0 < n) {
        int r = ex;
        int vv[4] = {v.x, v.y, v.z, v.w};
        for (int j = 0; j < 4 && i0 + j < n; j++) {
            rp[i0 + j] = r;
            cnt[i0 + j] = (float)vv[j];
            r += vv[j];
        }
    }
    if (blockIdx.x == 0 && tid == 0) rp[n] = bsum[nb];
}

// ---------------- CSR fill ----------------
__global__ void fill_kernel(const int* __restrict__ src, const int* __restrict__ dst, int E,
                            const int* __restrict__ rp, int* __restrict__ cur,
                            int* __restrict__ csr_src) {
    int t = blockIdx.x * blockDim.x + threadIdx.x;
    if (t >= E) return;
    int d = dst[t];
    int pos = atomicAdd(&cur[d], 1);
    csr_src[rp[d] + pos] = src[t];
}

// ---------------- pull gather: acc[r] = sum X[csr_src[e]] ----------------
template <int D>
__global__ __launch_bounds__(256) void gather_kernel(const int* __restrict__ rp,
                                                     const int* __restrict__ csr_src,
                                                     const float* __restrict__ X,
                                                     float* __restrict__ acc, int n) {
    constexpr int LPR = D / 4;
    constexpr int RPB = 256 / LPR;
    const int tid = threadIdx.x;
    const int r = blockIdx.x * RPB + tid / LPR;
    const int lane = tid % LPR;
    if (r >= n) return;
    const int e0 = rp[r], e1 = rp[r + 1];
    float4 s = make_float4(0.f, 0.f, 0.f, 0.f);
    for (int e = e0; e < e1; e++) {
        const int sidx = csr_src[e];
        float4 v = ((const float4*)(X + (long)sidx * D))[lane];
        s.x += v.x; s.y += v.y; s.z += v.z; s.w += v.w;
    }
    ((float4*)(acc + (long)r * D))[lane] = s;
}

// ---------------- fused fp32 GEMM: 64x128 tile, conflict-free microtile ----------------
// C[M, N] where N = G2?512:256.  Cols 0..255 (group0): +bias, opt relu, -> out0f/out0b.
// Cols 256..511 (group1): raw, -> out1 (Z). A = [A0(K0) | A1(K1)] (DUAL), A0 scaled by 1/cnt.
template <bool DUAL, bool SCALE0, bool RELU0, bool G2>
__global__ __launch_bounds__(256) void fgemm_kernel(
    int M, int K0, int K1,
    const float* __restrict__ A0, const float* __restrict__ A1,
    const float* __restrict__ W, const float* __restrict__ bias,
    const float* __restrict__ cnt,
    float* __restrict__ out0f, ushort* __restrict__ out0b, float* __restrict__ out1) {
    __shared__ float As[8][68];
    __shared__ float Ws[8][132];
    const int tid = threadIdx.x;
    const int row0 = blockIdx.x * 64, col0 = blockIdx.y * 128;
    const int Ktot = K0 + (DUAL ? K1 : 0);
    const int ty = tid >> 4, tx = tid & 15;   // rows ty*4+i, cols tx+16j

    float c[4][8];
#pragma unroll
    for (int i = 0; i < 4; i++)
#pragma unroll
        for (int j = 0; j < 8; j++) c[i][j] = 0.f;

    // A loader: threads 0..127, row = tid>>1 (0..63), off = (tid&1)*4
    const int alr = tid >> 1;
    const int aoff = (tid & 1) * 4;
    const int garow = row0 + alr;
    const int arow_c = (garow < M) ? garow : (M - 1);
    float scale0 = 1.f;
    if (SCALE0 && tid < 128) {
        float cv = (garow < M) ? cnt[garow] : 1.f;
        scale0 = 1.f / fmaxf(cv, 1.f);
    }
    // W loader: all threads, W-row = tid>>1 (0..127), off = (tid&1)*4
    const int wlr = tid >> 1;
    const int woff = (tid & 1) * 4;
    const long wbase = (long)(col0 + wlr) * Ktot + woff;

    for (int k0 = 0; k0 < Ktot; k0 += 8) {
        float4 av = make_float4(0.f, 0.f, 0.f, 0.f);
        if (tid < 128) {
            int k = k0 + aoff;
            if (!DUAL || k < K0) {
                av = *(const float4*)(A0 + (long)arow_c * K0 + k);
                if (SCALE0) { av.x *= scale0; av.y *= scale0; av.z *= scale0; av.w *= scale0; }
            } else {
                av = *(const float4*)(A1 + (long)arow_c * K1 + (k - K0));
            }
        }
        float4 wv = *(const float4*)(W + wbase + k0);

        __syncthreads();
        if (tid < 128) {
            As[aoff + 0][alr] = av.x; As[aoff + 1][alr] = av.y;
            As[aoff + 2][alr] = av.z; As[aoff + 3][alr] = av.w;
        }
        Ws[woff + 0][wlr] = wv.x; Ws[woff + 1][wlr] = wv.y;
        Ws[woff + 2][wlr] = wv.z; Ws[woff + 3][wlr] = wv.w;
        __syncthreads();

#pragma unroll
        for (int kk = 0; kk < 8; kk++) {
            float a[4], b[8];
#pragma unroll
            for (int i = 0; i < 4; i++) a[i] = As[kk][ty * 4 + i];
#pragma unroll
            for (int j = 0; j < 8; j++) b[j] = Ws[kk][16 * j + tx];
#pragma unroll
            for (int i = 0; i < 4; i++)
#pragma unroll
                for (int j = 0; j < 8; j++) c[i][j] += a[i] * b[j];
        }
    }

    const bool g1 = G2 && (col0 >= 256);
    const bool w0f = (out0f != nullptr), w0b = (out0b != nullptr);
#pragma unroll
    for (int i = 0; i < 4; i++) {
        int row = row0 + ty * 4 + i;
        if (row >= M) continue;
#pragma unroll
        for (int j = 0; j < 8; j++) {
            int col = col0 + 16 * j + tx;
            float v = c[i][j];
            if (!g1) {
                int cc = col & 255;
                v += bias[cc];
                if (RELU0) v = fmaxf(v, 0.f);
                if (w0f) out0f[(long)row * 256 + cc] = v;
                if (w0b) out0b[(long)row * 256 + cc] = f2bf(v);
            } else {
                out1[(long)row * 256 + (col - 256)] = v;
            }
        }
    }
}

// ---------------- bf16 MFMA GEMM: Cb[M,256] = relu(A@W^T + bias + accp/cnt) ----------------
template <int K>
__global__ __launch_bounds__(256, 2) void mfma_gemm_kernel(
    int M, const ushort* __restrict__ A, const ushort* __restrict__ W,
    const float* __restrict__ bias, const float* __restrict__ cnt,
    const float* __restrict__ accp, ushort* __restrict__ Cb) {
    constexpr int RS = 40;
    __shared__ ushort Als[128 * RS];
    __shared__ ushort Wls[128 * RS];
    const int tid = threadIdx.x;
    const int m0 = blockIdx.x * 128, n0 = blockIdx.y * 128;
    const int lane = tid & 63, w = tid >> 6;
    const int wm = w >> 1, wn = w & 1;
    const int m16 = lane & 15, q = lane >> 4;

    f32x4 acc[4][4] = {};

    for (int k0 = 0; k0 < K; k0 += 32) {
        bf16x8 a_st[2], w_st[2];
#pragma unroll
        for (int r = 0; r < 2; r++) {
            int chunk = tid + r * 256;
            int row = chunk >> 2, off = (chunk & 3) * 8;
            int ga = min(m0 + row, M - 1);
            a_st[r] = *(const bf16x8*)(A + (size_t)ga * K + k0 + off);
            w_st[r] = *(const bf16x8*)(W + (size_t)(n0 + row) * K + k0 + off);
        }
        __syncthreads();
#pragma unroll
        for (int r = 0; r < 2; r++) {
            int chunk = tid + r * 256;
            int row = chunk >> 2, off = (chunk & 3) * 8;
            *(bf16x8*)(&Als[row * RS + off]) = a_st[r];
            *(bf16x8*)(&Wls[row * RS + off]) = w_st[r];
        }
        __syncthreads();
        bf16x8 af[4], bf[4];
#pragma unroll
        for (int t = 0; t < 4; t++) {
            af[t] = *(const bf16x8*)(&Als[(wm * 64 + t * 16 + m16) * RS + q * 8]);
            bf[t] = *(const bf16x8*)(&Wls[(wn * 64 + t * 16 + m16) * RS + q * 8]);
        }
#pragma unroll
        for (int mt = 0; mt < 4; mt++)
#pragma unroll
            for (int nt = 0; nt < 4; nt++)
                acc[mt][nt] = __builtin_amdgcn_mfma_f32_16x16x32_bf16(af[mt], bf[nt], acc[mt][nt], 0, 0, 0);
    }

#pragma unroll
    for (int mt = 0; mt < 4; mt++) {
#pragma unroll
        for (int i = 0; i < 4; i++) {
            int row = m0 + wm * 64 + mt * 16 + q * 4 + i;
            if (row >= M) continue;
            float es = 1.f / fmaxf(cnt[row], 1.f);
#pragma unroll
            for (int nt = 0; nt < 4; nt++) {
                int col = n0 + wn * 64 + nt * 16 + m16;
                float v = acc[mt][nt][i] + bias[col] + accp[(size_t)row * 256 + col] * es;
                Cb[(size_t)row * 256 + col] = f2bf(fmaxf(v, 0.f));
            }
        }
    }
}

// ---------------- fused head ----------------
__global__ __launch_bounds__(256, 2) void mfma_head_kernel(
    const ushort* __restrict__ hp, const ushort* __restrict__ hm, const ushort* __restrict__ ht,
    const int* __restrict__ pp, const int* __restrict__ pm, const int* __restrict__ pt,
    const ushort* __restrict__ W1, const float* __restrict__ b1,
    const float* __restrict__ W2, const float* __restrict__ b2,
    float* __restrict__ out) {
    constexpr int RS = 40;
    __shared__ ushort Als[64 * RS];
    __shared__ ushort Wls[256 * RS];
    __shared__ int pidx[3][64];
    __shared__ float b1s[256], W2s[256];
    __shared__ float partial[64][65];

    const int tid = threadIdx.x;
    const int row0 = blockIdx.x * 64;
    if (tid < 64) {
        int i = row0 + tid, ii = (i < BB) ? i : 0;
        pidx[0][tid] = pp[ii]; pidx[1][tid] = pm[ii]; pidx[2][tid] = pt[ii];
    }
    b1s[tid] = b1[tid];
    W2s[tid] = W2[tid];
    __syncthreads();

    const int lane = tid & 63, w = tid >> 6;
    const int m16 = lane & 15, q = lane >> 4;
    const int arow = tid >> 2, aoff = (tid & 3) * 8;

    f32x4 acc[4][4] = {};

    for (int k0 = 0; k0 < 768; k0 += 32) {
        const int seg = k0 >> 8, ko = k0 & 255;
        const ushort* T = (seg == 0) ? hp : (seg == 1) ? hm : ht;
        const int ridx = pidx[seg][arow];
        bf16x8 a_st = *(const bf16x8*)(T + (size_t)ridx * 256 + ko + aoff);
        bf16x8 w_st[4];
#pragma unroll
        for (int r = 0; r < 4; r++) {
            int chunk = tid + r * 256;
            int row = chunk >> 2, off = (chunk & 3) * 8;
            w_st[r] = *(const bf16x8*)(W1 + (size_t)row * 768 + k0 + off);
        }
        __syncthreads();
        *(bf16x8*)(&Als[arow * RS + aoff]) = a_st;
#pragma unroll
        for (int r = 0; r < 4; r++) {
            int chunk = tid + r * 256;
            int row = chunk >> 2, off = (chunk & 3) * 8;
            *(bf16x8*)(&Wls[row * RS + off]) = w_st[r];
        }
        __syncthreads();
        bf16x8 af[4], bfr[4];
#pragma unroll
        for (int t = 0; t < 4; t++) {
            af[t] = *(const bf16x8*)(&Als[(t * 16 + m16) * RS + q * 8]);
            bfr[t] = *(const bf16x8*)(&Wls[(w * 64 + t * 16 + m16) * RS + q * 8]);
        }
#pragma unroll
        for (int mt = 0; mt < 4; mt++)
#pragma unroll
            for (int nt = 0; nt < 4; nt++)
                acc[mt][nt] = __builtin_amdgcn_mfma_f32_16x16x32_bf16(af[mt], bfr[nt], acc[mt][nt], 0, 0, 0);
    }

#pragma unroll
    for (int mt = 0; mt < 4; mt++) {
#pragma unroll
        for (int i = 0; i < 4; i++) {
            int rloc = mt * 16 + q * 4 + i;
            float p = 0.f;
#pragma unroll
            for (int nt = 0; nt < 4; nt++) {
                int col = w * 64 + nt * 16 + m16;
                float h = acc[mt][nt][i] + b1s[col];
                h = fmaxf(h, 0.f);
                p += h * W2s[col];
            }
            partial[rloc][(w << 4) | m16] = p;
        }
    }
    __syncthreads();
    if (tid < 64) {
        float s = 0.f;
#pragma unroll
        for (int j = 0; j < 64; j++) s += partial[tid][j];
        int r = row0 + tid;
        if (r < BB) out[r] = s + b2[0];
    }
}

// ---------------- launch ----------------
extern "C" void kernel_launch(void* const* d_in, const int* in_sizes, int n_in,
                              void* d_out, int out_size, void* d_ws, size_t ws_size,
                              hipStream_t stream) {
    const float* emb_pep = (const float*)d_in[0];
    const float* emb_mhc = (const float*)d_in[1];
    const float* emb_tcr = (const float*)d_in[2];
    const int* src_pm = (const int*)d_in[3];
    const int* dst_pm = (const int*)d_in[4];
    const int* src_mt = (const int*)d_in[5];
    const int* dst_mt = (const int*)d_in[6];
    const int* pack_pep = (const int*)d_in[7];
    const int* pack_mhc = (const int*)d_in[8];
    const int* pack_tcr = (const int*)d_in[9];
    const float* l1_pm_Wl = (const float*)d_in[10];
    const float* l1_pm_bl = (const float*)d_in[11];
    const float* l1_pm_Wr = (const float*)d_in[12];
    const float* l1_mt_Wl = (const float*)d_in[13];
    const float* l1_mt_bl = (const float*)d_in[14];
    const float* l1_mt_Wr = (const float*)d_in[15];
    const float* l2_pm_Wl = (const float*)d_in[16];
    const float* l2_pm_bl = (const float*)d_in[17];
    const float* l2_pm_Wr = (const float*)d_in[18];
    const float* l2_mt_Wl = (const float*)d_in[19];
    const float* l2_mt_bl = (const float*)d_in[20];
    const float* l2_mt_Wr = (const float*)d_in[21];
    const float* proj_W = (const float*)d_in[22];
    const float* proj_b = (const float*)d_in[23];
    const float* head_W1 = (const float*)d_in[24];
    const float* head_b1 = (const float*)d_in[25];
    const float* head_W2 = (const float*)d_in[26];
    const float* head_b2 = (const float*)d_in[27];
    float* out = (float*)d_out;

    // ---------------- workspace layout ----------------
    int* ib = (int*)d_ws;
    int* deg_pm = ib;                 // 5000
    int* cur_pm = ib + 5000;          // 5000
    int* deg_mt = ib + 10000;         // 100000
    int* cur_mt = ib + 110000;        // 100000   [zero region: first 210000 ints]
    int* rp_pm  = ib + 210000;        // 5001 (pad 5008)
    int* rp_mt  = ib + 215008;        // 100001 (pad 100008)
    int* csr_pm = ib + 315016;        // 200000
    int* csr_mt = ib + 515016;        // 400000
    int* bsum_pm = ib + 915016;       // 160
    int* bsum_mt = ib + 915176;       // 160 -> ints end at 915336

    float* f = (float*)(ib + 915336);
    float* cnt_pm = f;                // 5000
    float* cnt_mt = f + 5000;         // 100000
    float* agg_pm = f + 105000;       // 640000
    float* Z      = f + 745000;       // 1280000 (Z1 then Z2)
    float* mhc1   = f + 2025000;      // 1280000
    float* acc    = f + 3305000;      // 25600000
    float* Wcat1  = f + 28905000;     // 131072  (512 x 256)
    float* Wcat2  = f + 29036072;     // 196608  (512 x 384)
    // floats end at f + 29232680

    ushort* u = (ushort*)(f + 29232680);
    ushort* Wr1_b   = u;              // 32768
    ushort* Wr2_b   = u + 32768;      // 65536
    ushort* W1_b    = u + 98304;      // 196608
    ushort* hp_b    = u + 294912;     // 5120000
    ushort* mhc2_b  = u + 5414912;    // 1280000
    ushort* tcr1_b  = u + 6694912;    // 25600000
    ushort* ushare  = u + 32294912;   // 25600000
    ushort* emb_tcr_b = ushare;
    ushort* tcr2_b    = ushare;

    // ---------------- setup: Wcat builds + bf16 conversions ----------------
    wcat_kernel<<<(512 * 256 + 255) / 256, 256, 0, stream>>>(l1_pm_Wl, l1_pm_Wr, l1_mt_Wl, 128, 256, Wcat1);
    wcat_kernel<<<(512 * 384 + 255) / 256, 256, 0, stream>>>(l2_pm_Wl, l2_pm_Wr, l2_mt_Wl, 256, 384, Wcat2);
    cvt_kernel<<<(3200000 + 255) / 256, 256, 0, stream>>>((const float4*)emb_tcr, (ushort4*)emb_tcr_b, 3200000);
    cvt_kernel<<<(8192 + 255) / 256, 256, 0, stream>>>((const float4*)l1_mt_Wr, (ushort4*)Wr1_b, 8192);
    cvt_kernel<<<(16384 + 255) / 256, 256, 0, stream>>>((const float4*)l2_mt_Wr, (ushort4*)Wr2_b, 16384);
    cvt_kernel<<<(49152 + 255) / 256, 256, 0, stream>>>((const float4*)head_W1, (ushort4*)W1_b, 49152);

    // ---------------- CSR build ----------------
    zero_int_kernel<<<(210000 + 255) / 256, 256, 0, stream>>>(ib, 210000);
    hist_kernel<<<(EPM + 255) / 256, 256, 0, stream>>>(dst_pm, EPM, deg_pm);
    hist_kernel<<<(EMT + 255) / 256, 256, 0, stream>>>(dst_mt, EMT, deg_mt);
    const int nb_pm = (NMHC + 1023) / 1024;   // 5
    const int nb_mt = (NTCR + 1023) / 1024;   // 98
    blocksum_kernel<<<nb_pm, 256, 0, stream>>>(deg_pm, NMHC, bsum_pm);
    blocksum_kernel<<<nb_mt, 256, 0, stream>>>(deg_mt, NTCR, bsum_mt);
    scanb_kernel<<<1, 128, 0, stream>>>(bsum_pm, nb_pm);
    scanb_kernel<<<1, 128, 0, stream>>>(bsum_mt, nb_mt);
    emit_kernel<<<nb_pm, 256, 0, stream>>>(deg_pm, NMHC, bsum_pm, nb_pm, rp_pm, cnt_pm);
    emit_kernel<<<nb_mt, 256, 0, stream>>>(deg_mt, NTCR, bsum_mt, nb_mt, rp_mt, cnt_mt);
    fill_kernel<<<(EPM + 255) / 256, 256, 0, stream>>>(src_pm, dst_pm, EPM, rp_pm, cur_pm, csr_pm);
    fill_kernel<<<(EMT + 255) / 256, 256, 0, stream>>>(src_mt, dst_mt, EMT, rp_mt, cur_mt, csr_mt);

    // ---------------- pipeline ----------------
    gather_kernel<128><<<(NMHC + 7) / 8, 256, 0, stream>>>(rp_pm, csr_pm, emb_pep, agg_pm, NMHC);

    // fused layer1: cols 0-255 -> mhc1 (fp32, relu);  cols 256-511 -> Z = emb_mhc @ l1_mt_Wl^T
    fgemm_kernel<true, true, true, true><<<dim3((NMHC + 63) / 64, 4), 256, 0, stream>>>(
        NMHC, 128, 128, agg_pm, emb_mhc, Wcat1, l1_pm_bl, cnt_pm, mhc1, nullptr, Z);
    // acc = segsum(Z[src_mt] -> dst_mt)
    gather_kernel<256><<<(NTCR + 3) / 4, 256, 0, stream>>>(rp_mt, csr_mt, Z, acc, NTCR);
    // tcr1_b = relu( emb_tcr_b @ Wr1_b^T + bl + acc/cnt )   [MFMA]
    mfma_gemm_kernel<128><<<dim3((NTCR + 127) / 128, 2), 256, 0, stream>>>(
        NTCR, emb_tcr_b, Wr1_b, l1_mt_bl, cnt_mt, acc, tcr1_b);

    // fused layer2: cols 0-255 -> mhc2_b (bf16, relu);  cols 256-511 -> Z = mhc1 @ l2_mt_Wl^T
    fgemm_kernel<true, true, true, true><<<dim3((NMHC + 63) / 64, 4), 256, 0, stream>>>(
        NMHC, 128, 256, agg_pm, mhc1, Wcat2, l2_pm_bl, cnt_pm, nullptr, mhc2_b, Z);
    // acc = segsum(Z[src_mt] -> dst_mt)
    gather_kernel<256><<<(NTCR + 3) / 4, 256, 0, stream>>>(rp_mt, csr_mt, Z, acc, NTCR);
    // tcr2_b = relu( tcr1_b @ Wr2_b^T + bl + acc/cnt )   [MFMA]
    mfma_gemm_kernel<256><<<dim3((NTCR + 127) / 128, 2), 256, 0, stream>>>(
        NTCR, tcr1_b, Wr2_b, l2_mt_bl, cnt_mt, acc, tcr2_b);

    // hp_b = emb_pep @ proj_W^T + proj_b  -> bf16 (no relu)
    fgemm_kernel<false, false, false, false><<<dim3((NPEP + 63) / 64, 2), 256, 0, stream>>>(
        NPEP, 128, 0, emb_pep, nullptr, proj_W, proj_b, nullptr, nullptr, hp_b, nullptr);

    // head
    mfma_head_kernel<<<(BB + 63) / 64, 256, 0, stream>>>(
        hp_b, mhc2_b, tcr2_b, pack_pep, pack_mhc, pack_tcr, W1_b, head_b1, head_W2, head_b2, out);
}

// Round 6
// 551.331 us; speedup vs baseline: 7.7822x; 1.1792x over previous
//
#include <hip/hip_runtime.h>

// ---------------- problem constants ----------------
constexpr int NPEP = 20000, NMHC = 5000, NTCR = 100000;
constexpr int EPM = 200000, EMT = 400000, BB = 50000;

typedef __attribute__((ext_vector_type(8))) short bf16x8;
typedef __attribute__((ext_vector_type(4))) float f32x4;

__device__ inline ushort f2bf(float x) {
    union { float f; unsigned u; } v; v.f = x;
    unsigned r = (v.u + 0x7FFF + ((v.u >> 16) & 1)) >> 16;
    return (ushort)r;
}
__device__ inline float bf2f(ushort b) {
    union { unsigned u; float f; } t; t.u = ((unsigned)b) << 16; return t.f;
}
__device__ inline void bf2x2(unsigned u, float& a, float& b) {
    union { unsigned x; float f; } t1, t2;
    t1.x = u << 16; t2.x = u & 0xffff0000u;
    a = t1.f; b = t2.f;
}

// ---------------- zero ints ----------------
__global__ void zero_int_kernel(int* __restrict__ p, int n) {
    int i = blockIdx.x * blockDim.x + threadIdx.x;
    if (i < n) p[i] = 0;
}

// ---------------- fp32 -> bf16 convert ----------------
__global__ void cvt_kernel(const float4* __restrict__ in, ushort4* __restrict__ out, int n4) {
    int i = blockIdx.x * blockDim.x + threadIdx.x;
    if (i < n4) {
        float4 v = in[i];
        out[i] = make_ushort4(f2bf(v.x), f2bf(v.y), f2bf(v.z), f2bf(v.w));
    }
}

// ---------------- emb_mhc fp32 -> bf16 into Acat1 cols 128..255 (stride 256) ----------------
__global__ void cvts_kernel(const float4* __restrict__ in, ushort* __restrict__ out, int n4) {
    int i4 = blockIdx.x * blockDim.x + threadIdx.x;
    if (i4 >= n4) return;
    int r = i4 >> 5, c4 = (i4 & 31) * 4;
    float4 v = in[i4];
    *(ushort4*)(out + (size_t)r * 256 + 128 + c4) =
        make_ushort4(f2bf(v.x), f2bf(v.y), f2bf(v.z), f2bf(v.w));
}

// ---------------- mean_pm bf16 into Acat1 cols 0..127 and Acat2 cols 0..127 ----------------
__global__ void meanb_kernel(const float4* __restrict__ agg, const float* __restrict__ cnt,
                             ushort* __restrict__ A1, ushort* __restrict__ A2, int n4) {
    int i4 = blockIdx.x * blockDim.x + threadIdx.x;
    if (i4 >= n4) return;
    int r = i4 >> 5, c4 = (i4 & 31) * 4;
    float sc = 1.f / fmaxf(cnt[r], 1.f);
    float4 v = agg[i4];
    ushort4 o = make_ushort4(f2bf(v.x * sc), f2bf(v.y * sc), f2bf(v.z * sc), f2bf(v.w * sc));
    *(ushort4*)(A1 + (size_t)r * 256 + c4) = o;
    *(ushort4*)(A2 + (size_t)r * 384 + c4) = o;
}

// ---------------- concatenated padded weight [512 x Ktot] -> bf16 ----------------
__global__ void wcatb_kernel(const float* __restrict__ Wpm_l, const float* __restrict__ Wpm_r,
                             const float* __restrict__ Wmt_l, int K1, int Ktot,
                             ushort* __restrict__ out) {
    int idx = blockIdx.x * blockDim.x + threadIdx.x;
    if (idx >= 512 * Ktot) return;
    int r = idx / Ktot, k = idx - r * Ktot;
    float v;
    if (r < 256) v = (k < 128) ? Wpm_l[r * 128 + k] : Wpm_r[r * K1 + (k - 128)];
    else         v = (k < 128) ? 0.f : Wmt_l[(r - 256) * K1 + (k - 128)];
    out[idx] = f2bf(v);
}

// ---------------- degree histogram ----------------
__global__ void hist_kernel(const int* __restrict__ dst, int E, int* __restrict__ deg) {
    int t = blockIdx.x * blockDim.x + threadIdx.x;
    if (t < E) atomicAdd(&deg[dst[t]], 1);
}

// ---------------- 3-phase device-wide exclusive scan ----------------
__global__ __launch_bounds__(256) void blocksum_kernel(const int* __restrict__ deg, int n,
                                                       int* __restrict__ bsum) {
    __shared__ int red[256];
    const int tid = threadIdx.x;
    const int base = blockIdx.x * 1024;
    int s = 0;
#pragma unroll
    for (int j = 0; j < 4; j++) {
        int i = base + tid + j * 256;
        if (i < n) s += deg[i];
    }
    red[tid] = s;
    __syncthreads();
    for (int off = 128; off > 0; off >>= 1) {
        if (tid < off) red[tid] += red[tid + off];
        __syncthreads();
    }
    if (tid == 0) bsum[blockIdx.x] = red[0];
}

__global__ __launch_bounds__(128) void scanb_kernel(int* __restrict__ bsum, int nb) {
    __shared__ int s[128];
    const int tid = threadIdx.x;
    int v = (tid < nb) ? bsum[tid] : 0;
    s[tid] = v;
    __syncthreads();
    for (int off = 1; off < 128; off <<= 1) {
        int t = (tid >= off) ? s[tid - off] : 0;
        __syncthreads();
        s[tid] += t;
        __syncthreads();
    }
    if (tid < nb) bsum[tid] = (tid > 0) ? s[tid - 1] : 0;
    if (tid == 0) bsum[nb] = s[nb - 1];
}

__global__ __launch_bounds__(256) void emit_kernel(const int* __restrict__ deg, int n,
                                                   const int* __restrict__ bsum, int nb,
                                                   int* __restrict__ rp, float* __restrict__ cnt) {
    __shared__ int tsum[256];
    const int tid = threadIdx.x;
    const int base = blockIdx.x * 1024;
    const int i0 = base + tid * 4;
    int4 v = make_int4(0, 0, 0, 0);
    if (i0 + 3 < n) v = *(const int4*)(deg + i0);
    else if (i0 < n) {
        int t[4] = {0, 0, 0, 0};
        for (int j = 0; j < 4 && i0 + j < n; j++) t[j] = deg[i0 + j];
        v = make_int4(t[0], t[1], t[2], t[3]);
    }
    int s = v.x + v.y + v.z + v.w;
    tsum[tid] = s;
    __syncthreads();
    for (int off = 1; off < 256; off <<= 1) {
        int t = (tid >= off) ? tsum[tid - off] : 0;
        __syncthreads();
        tsum[tid] += t;
        __syncthreads();
    }
    int ex = ((tid > 0) ? tsum[tid - 1] : 0) + bsum[blockIdx.x];
    if (i0 + 3 < n) {
        int r1 = ex + v.x, r2 = r1 + v.y, r3 = r2 + v.z;
        *(int4*)(rp + i0) = make_int4(ex, r1, r2, r3);
        *(float4*)(cnt + i0) = make_float4((float)v.x, (float)v.y, (float)v.z, (float)v.w);
    } else if (i0 < n) {
        int r = ex;
        int vv[4] = {v.x, v.y, v.z, v.w};
        for (int j = 0; j < 4 && i0 + j < n; j++) {
            rp[i0 + j] = r;
            cnt[i0 + j] = (float)vv[j];
            r += vv[j];
        }
    }
    if (blockIdx.x == 0 && tid == 0) rp[n] = bsum[nb];
}

// ---------------- CSR fill ----------------
__global__ void fill_kernel(const int* __restrict__ src, const int* __restrict__ dst, int E,
                            const int* __restrict__ rp, int* __restrict__ cur,
                            int* __restrict__ csr_src) {
    int t = blockIdx.x * blockDim.x + threadIdx.x;
    if (t >= E) return;
    int d = dst[t];
    int pos = atomicAdd(&cur[d], 1);
    csr_src[rp[d] + pos] = src[t];
}

// ---------------- fp32 pull gather (pm relation, D=128) ----------------
__global__ __launch_bounds__(256) void gather_kernel(const int* __restrict__ rp,
                                                     const int* __restrict__ csr_src,
                                                     const float* __restrict__ X,
                                                     float* __restrict__ acc, int n) {
    const int tid = threadIdx.x;
    const int r = blockIdx.x * 8 + tid / 32;
    const int lane = tid % 32;
    if (r >= n) return;
    const int e0 = rp[r], e1 = rp[r + 1];
    float4 s = make_float4(0.f, 0.f, 0.f, 0.f);
    for (int e = e0; e < e1; e++) {
        const int sidx = csr_src[e];
        float4 v = ((const float4*)(X + (long)sidx * 128))[lane];
        s.x += v.x; s.y += v.y; s.z += v.z; s.w += v.w;
    }
    ((float4*)(acc + (long)r * 128))[lane] = s;
}

// ---------------- bf16 pull gather (mt relation, D=256 bf16 in/out) ----------------
__global__ __launch_bounds__(256) void gatherb_kernel(const int* __restrict__ rp,
                                                      const int* __restrict__ csr_src,
                                                      const ushort* __restrict__ Zb,
                                                      ushort* __restrict__ accb, int n) {
    const int tid = threadIdx.x;
    const int r = blockIdx.x * 8 + (tid >> 5);
    const int lane = tid & 31;
    if (r >= n) return;
    const int e0 = rp[r], e1 = rp[r + 1];
    float s[8] = {};
    for (int e = e0; e < e1; e++) {
        const int sidx = csr_src[e];
        uint4 u = *(const uint4*)(Zb + (size_t)sidx * 256 + lane * 8);
        float a, b;
        bf2x2(u.x, a, b); s[0] += a; s[1] += b;
        bf2x2(u.y, a, b); s[2] += a; s[3] += b;
        bf2x2(u.z, a, b); s[4] += a; s[5] += b;
        bf2x2(u.w, a, b); s[6] += a; s[7] += b;
    }
    ushort o[8];
#pragma unroll
    for (int j = 0; j < 8; j++) o[j] = f2bf(s[j]);
    uint4 w;
    w.x = (unsigned)o[0] | ((unsigned)o[1] << 16);
    w.y = (unsigned)o[2] | ((unsigned)o[3] << 16);
    w.z = (unsigned)o[4] | ((unsigned)o[5] << 16);
    w.w = (unsigned)o[6] | ((unsigned)o[7] << 16);
    *(uint4*)(accb + (size_t)r * 256 + lane * 8) = w;
}

// ---------------- bf16 MFMA fused GEMM ----------------
// C[M, gridDim.y*128] = A[M,K] @ W^T. Col-blocks < NB0: +bias, opt relu -> out0 (row stride s0).
// Col-blocks >= NB0 (if G2): raw -> out1 (row stride 256, col offset -NB0*128).
template <int K, int NB0, bool RELU0, bool G2>
__global__ __launch_bounds__(256, 2) void mfma_fused_kernel(
    int M, const ushort* __restrict__ A, const ushort* __restrict__ W,
    const float* __restrict__ bias,
    ushort* __restrict__ out0, int s0, ushort* __restrict__ out1) {
    constexpr int RS = 40;
    __shared__ ushort Als[128 * RS];
    __shared__ ushort Wls[128 * RS];
    const int tid = threadIdx.x;
    const int m0 = blockIdx.x * 128, n0 = blockIdx.y * 128;
    const int lane = tid & 63, w = tid >> 6;
    const int wm = w >> 1, wn = w & 1;
    const int m16 = lane & 15, q = lane >> 4;

    f32x4 acc[4][4] = {};

    for (int k0 = 0; k0 < K; k0 += 32) {
        bf16x8 a_st[2], w_st[2];
#pragma unroll
        for (int r = 0; r < 2; r++) {
            int chunk = tid + r * 256;
            int row = chunk >> 2, off = (chunk & 3) * 8;
            int ga = min(m0 + row, M - 1);
            a_st[r] = *(const bf16x8*)(A + (size_t)ga * K + k0 + off);
            w_st[r] = *(const bf16x8*)(W + (size_t)(n0 + row) * K + k0 + off);
        }
        __syncthreads();
#pragma unroll
        for (int r = 0; r < 2; r++) {
            int chunk = tid + r * 256;
            int row = chunk >> 2, off = (chunk & 3) * 8;
            *(bf16x8*)(&Als[row * RS + off]) = a_st[r];
            *(bf16x8*)(&Wls[row * RS + off]) = w_st[r];
        }
        __syncthreads();
        bf16x8 af[4], bf[4];
#pragma unroll
        for (int t = 0; t < 4; t++) {
            af[t] = *(const bf16x8*)(&Als[(wm * 64 + t * 16 + m16) * RS + q * 8]);
            bf[t] = *(const bf16x8*)(&Wls[(wn * 64 + t * 16 + m16) * RS + q * 8]);
        }
#pragma unroll
        for (int mt = 0; mt < 4; mt++)
#pragma unroll
            for (int nt = 0; nt < 4; nt++)
                acc[mt][nt] = __builtin_amdgcn_mfma_f32_16x16x32_bf16(af[mt], bf[nt], acc[mt][nt], 0, 0, 0);
    }

    const bool g1 = G2 && ((int)blockIdx.y >= NB0);
#pragma unroll
    for (int mt = 0; mt < 4; mt++) {
#pragma unroll
        for (int i = 0; i < 4; i++) {
            int row = m0 + wm * 64 + mt * 16 + q * 4 + i;
            if (row >= M) continue;
#pragma unroll
            for (int nt = 0; nt < 4; nt++) {
                int col = n0 + wn * 64 + nt * 16 + m16;
                float v = acc[mt][nt][i];
                if (!g1) {
                    v += bias[col];
                    if (RELU0) v = fmaxf(v, 0.f);
                    out0[(size_t)row * s0 + col] = f2bf(v);
                } else {
                    out1[(size_t)row * 256 + (col - NB0 * 128)] = f2bf(v);
                }
            }
        }
    }
}

// ---------------- bf16 MFMA GEMM (tcr): Cb = relu(A@W^T + bias + bf16acc/cnt) ----------------
template <int K>
__global__ __launch_bounds__(256, 2) void mfma_gemm_kernel(
    int M, const ushort* __restrict__ A, const ushort* __restrict__ W,
    const float* __restrict__ bias, const float* __restrict__ cnt,
    const ushort* __restrict__ accp, ushort* __restrict__ Cb) {
    constexpr int RS = 40;
    __shared__ ushort Als[128 * RS];
    __shared__ ushort Wls[128 * RS];
    const int tid = threadIdx.x;
    const int m0 = blockIdx.x * 128, n0 = blockIdx.y * 128;
    const int lane = tid & 63, w = tid >> 6;
    const int wm = w >> 1, wn = w & 1;
    const int m16 = lane & 15, q = lane >> 4;

    f32x4 acc[4][4] = {};

    for (int k0 = 0; k0 < K; k0 += 32) {
        bf16x8 a_st[2], w_st[2];
#pragma unroll
        for (int r = 0; r < 2; r++) {
            int chunk = tid + r * 256;
            int row = chunk >> 2, off = (chunk & 3) * 8;
            int ga = min(m0 + row, M - 1);
            a_st[r] = *(const bf16x8*)(A + (size_t)ga * K + k0 + off);
            w_st[r] = *(const bf16x8*)(W + (size_t)(n0 + row) * K + k0 + off);
        }
        __syncthreads();
#pragma unroll
        for (int r = 0; r < 2; r++) {
            int chunk = tid + r * 256;
            int row = chunk >> 2, off = (chunk & 3) * 8;
            *(bf16x8*)(&Als[row * RS + off]) = a_st[r];
            *(bf16x8*)(&Wls[row * RS + off]) = w_st[r];
        }
        __syncthreads();
        bf16x8 af[4], bf[4];
#pragma unroll
        for (int t = 0; t < 4; t++) {
            af[t] = *(const bf16x8*)(&Als[(wm * 64 + t * 16 + m16) * RS + q * 8]);
            bf[t] = *(const bf16x8*)(&Wls[(wn * 64 + t * 16 + m16) * RS + q * 8]);
        }
#pragma unroll
        for (int mt = 0; mt < 4; mt++)
#pragma unroll
            for (int nt = 0; nt < 4; nt++)
                acc[mt][nt] = __builtin_amdgcn_mfma_f32_16x16x32_bf16(af[mt], bf[nt], acc[mt][nt], 0, 0, 0);
    }

#pragma unroll
    for (int mt = 0; mt < 4; mt++) {
#pragma unroll
        for (int i = 0; i < 4; i++) {
            int row = m0 + wm * 64 + mt * 16 + q * 4 + i;
            if (row >= M) continue;
            float es = 1.f / fmaxf(cnt[row], 1.f);
#pragma unroll
            for (int nt = 0; nt < 4; nt++) {
                int col = n0 + wn * 64 + nt * 16 + m16;
                float v = acc[mt][nt][i] + bias[col] + bf2f(accp[(size_t)row * 256 + col]) * es;
                Cb[(size_t)row * 256 + col] = f2bf(fmaxf(v, 0.f));
            }
        }
    }
}

// ---------------- fused head ----------------
__global__ __launch_bounds__(256, 2) void mfma_head_kernel(
    const ushort* __restrict__ hp, const ushort* __restrict__ hm, const ushort* __restrict__ ht,
    const int* __restrict__ pp, const int* __restrict__ pm, const int* __restrict__ pt,
    const ushort* __restrict__ W1, const float* __restrict__ b1,
    const float* __restrict__ W2, const float* __restrict__ b2,
    float* __restrict__ out) {
    constexpr int RS = 40;
    __shared__ ushort Als[64 * RS];
    __shared__ ushort Wls[256 * RS];
    __shared__ int pidx[3][64];
    __shared__ float b1s[256], W2s[256];
    __shared__ float partial[64][65];

    const int tid = threadIdx.x;
    const int row0 = blockIdx.x * 64;
    if (tid < 64) {
        int i = row0 + tid, ii = (i < BB) ? i : 0;
        pidx[0][tid] = pp[ii]; pidx[1][tid] = pm[ii]; pidx[2][tid] = pt[ii];
    }
    b1s[tid] = b1[tid];
    W2s[tid] = W2[tid];
    __syncthreads();

    const int lane = tid & 63, w = tid >> 6;
    const int m16 = lane & 15, q = lane >> 4;
    const int arow = tid >> 2, aoff = (tid & 3) * 8;

    f32x4 acc[4][4] = {};

    for (int k0 = 0; k0 < 768; k0 += 32) {
        const int seg = k0 >> 8, ko = k0 & 255;
        const ushort* T = (seg == 0) ? hp : (seg == 1) ? hm : ht;
        const int ridx = pidx[seg][arow];
        bf16x8 a_st = *(const bf16x8*)(T + (size_t)ridx * 256 + ko + aoff);
        bf16x8 w_st[4];
#pragma unroll
        for (int r = 0; r < 4; r++) {
            int chunk = tid + r * 256;
            int row = chunk >> 2, off = (chunk & 3) * 8;
            w_st[r] = *(const bf16x8*)(W1 + (size_t)row * 768 + k0 + off);
        }
        __syncthreads();
        *(bf16x8*)(&Als[arow * RS + aoff]) = a_st;
#pragma unroll
        for (int r = 0; r < 4; r++) {
            int chunk = tid + r * 256;
            int row = chunk >> 2, off = (chunk & 3) * 8;
            *(bf16x8*)(&Wls[row * RS + off]) = w_st[r];
        }
        __syncthreads();
        bf16x8 af[4], bfr[4];
#pragma unroll
        for (int t = 0; t < 4; t++) {
            af[t] = *(const bf16x8*)(&Als[(t * 16 + m16) * RS + q * 8]);
            bfr[t] = *(const bf16x8*)(&Wls[(w * 64 + t * 16 + m16) * RS + q * 8]);
        }
#pragma unroll
        for (int mt = 0; mt < 4; mt++)
#pragma unroll
            for (int nt = 0; nt < 4; nt++)
                acc[mt][nt] = __builtin_amdgcn_mfma_f32_16x16x32_bf16(af[mt], bfr[nt], acc[mt][nt], 0, 0, 0);
    }

#pragma unroll
    for (int mt = 0; mt < 4; mt++) {
#pragma unroll
        for (int i = 0; i < 4; i++) {
            int rloc = mt * 16 + q * 4 + i;
            float p = 0.f;
#pragma unroll
            for (int nt = 0; nt < 4; nt++) {
                int col = w * 64 + nt * 16 + m16;
                float h = acc[mt][nt][i] + b1s[col];
                h = fmaxf(h, 0.f);
                p += h * W2s[col];
            }
            partial[rloc][(w << 4) | m16] = p;
        }
    }
    __syncthreads();
    if (tid < 64) {
        float s = 0.f;
#pragma unroll
        for (int j = 0; j < 64; j++) s += partial[tid][j];
        int r = row0 + tid;
        if (r < BB) out[r] = s + b2[0];
    }
}

// ---------------- launch ----------------
extern "C" void kernel_launch(void* const* d_in, const int* in_sizes, int n_in,
                              void* d_out, int out_size, void* d_ws, size_t ws_size,
                              hipStream_t stream) {
    const float* emb_pep = (const float*)d_in[0];
    const float* emb_mhc = (const float*)d_in[1];
    const float* emb_tcr = (const float*)d_in[2];
    const int* src_pm = (const int*)d_in[3];
    const int* dst_pm = (const int*)d_in[4];
    const int* src_mt = (const int*)d_in[5];
    const int* dst_mt = (const int*)d_in[6];
    const int* pack_pep = (const int*)d_in[7];
    const int* pack_mhc = (const int*)d_in[8];
    const int* pack_tcr = (const int*)d_in[9];
    const float* l1_pm_Wl = (const float*)d_in[10];
    const float* l1_pm_bl = (const float*)d_in[11];
    const float* l1_pm_Wr = (const float*)d_in[12];
    const float* l1_mt_Wl = (const float*)d_in[13];
    const float* l1_mt_bl = (const float*)d_in[14];
    const float* l1_mt_Wr = (const float*)d_in[15];
    const float* l2_pm_Wl = (const float*)d_in[16];
    const float* l2_pm_bl = (const float*)d_in[17];
    const float* l2_pm_Wr = (const float*)d_in[18];
    const float* l2_mt_Wl = (const float*)d_in[19];
    const float* l2_mt_bl = (const float*)d_in[20];
    const float* l2_mt_Wr = (const float*)d_in[21];
    const float* proj_W = (const float*)d_in[22];
    const float* proj_b = (const float*)d_in[23];
    const float* head_W1 = (const float*)d_in[24];
    const float* head_b1 = (const float*)d_in[25];
    const float* head_W2 = (const float*)d_in[26];
    const float* head_b2 = (const float*)d_in[27];
    float* out = (float*)d_out;

    // ---------------- workspace layout ----------------
    int* ib = (int*)d_ws;
    int* deg_pm = ib;                 // 5000
    int* cur_pm = ib + 5000;          // 5000
    int* deg_mt = ib + 10000;         // 100000
    int* cur_mt = ib + 110000;        // 100000   [zero region: first 210000 ints]
    int* rp_pm  = ib + 210000;        // 5001 (pad 5008)
    int* rp_mt  = ib + 215008;        // 100001 (pad 100008)
    int* csr_pm = ib + 315016;        // 200000
    int* csr_mt = ib + 515016;        // 400000
    int* bsum_pm = ib + 915016;       // 160
    int* bsum_mt = ib + 915176;       // 160 -> ints end at 915336 (pad to 915344)

    float* f = (float*)(ib + 915344);
    float* cnt_pm = f;                // 5000
    float* cnt_mt = f + 5000;         // 100000
    float* agg_pm = f + 105000;       // 640000
    // floats end at f + 745000  (745000*4 bytes, 16B-aligned)

    ushort* u = (ushort*)(f + 745000);
    ushort* Wcat1_b  = u;             // 131072  (512x256)
    ushort* Wcat2_b  = u + 131072;    // 196608  (512x384)
    ushort* Acat1    = u + 327680;    // 1280000 (5000x256: [mean_pm | emb_mhc])
    ushort* Acat2    = u + 1607680;   // 1920000 (5000x384: [mean_pm | mhc1])
    ushort* Zb       = u + 3527680;   // 1280000
    ushort* mhc2_b   = u + 4807680;   // 1280000
    ushort* hp_b     = u + 6087680;   // 5120000
    ushort* emb_pep_b= u + 11207680;  // 2560000
    ushort* proj_W_b = u + 13767680;  // 32768
    ushort* Wr1_b    = u + 13800448;  // 32768
    ushort* Wr2_b    = u + 13833216;  // 65536
    ushort* W1_b     = u + 13898752;  // 196608
    ushort* acc_b    = u + 14095360;  // 25600000
    ushort* tcr1_b   = u + 39695360;  // 25600000
    ushort* ushare   = u + 65295360;  // 25600000 (emb_tcr_b then tcr2_b)
    ushort* emb_tcr_b = ushare;
    ushort* tcr2_b    = ushare;
    // total ~189 MB

    // ---------------- CSR build ----------------
    zero_int_kernel<<<(210000 + 255) / 256, 256, 0, stream>>>(ib, 210000);
    hist_kernel<<<(EPM + 255) / 256, 256, 0, stream>>>(dst_pm, EPM, deg_pm);
    hist_kernel<<<(EMT + 255) / 256, 256, 0, stream>>>(dst_mt, EMT, deg_mt);
    const int nb_pm = (NMHC + 1023) / 1024;   // 5
    const int nb_mt = (NTCR + 1023) / 1024;   // 98
    blocksum_kernel<<<nb_pm, 256, 0, stream>>>(deg_pm, NMHC, bsum_pm);
    blocksum_kernel<<<nb_mt, 256, 0, stream>>>(deg_mt, NTCR, bsum_mt);
    scanb_kernel<<<1, 128, 0, stream>>>(bsum_pm, nb_pm);
    scanb_kernel<<<1, 128, 0, stream>>>(bsum_mt, nb_mt);
    emit_kernel<<<nb_pm, 256, 0, stream>>>(deg_pm, NMHC, bsum_pm, nb_pm, rp_pm, cnt_pm);
    emit_kernel<<<nb_mt, 256, 0, stream>>>(deg_mt, NTCR, bsum_mt, nb_mt, rp_mt, cnt_mt);
    fill_kernel<<<(EPM + 255) / 256, 256, 0, stream>>>(src_pm, dst_pm, EPM, rp_pm, cur_pm, csr_pm);
    fill_kernel<<<(EMT + 255) / 256, 256, 0, stream>>>(src_mt, dst_mt, EMT, rp_mt, cur_mt, csr_mt);

    // ---------------- bf16 weight/embedding prep ----------------
    wcatb_kernel<<<(512 * 256 + 255) / 256, 256, 0, stream>>>(l1_pm_Wl, l1_pm_Wr, l1_mt_Wl, 128, 256, Wcat1_b);
    wcatb_kernel<<<(512 * 384 + 255) / 256, 256, 0, stream>>>(l2_pm_Wl, l2_pm_Wr, l2_mt_Wl, 256, 384, Wcat2_b);
    cvt_kernel<<<(3200000 + 255) / 256, 256, 0, stream>>>((const float4*)emb_tcr, (ushort4*)emb_tcr_b, 3200000);
    cvt_kernel<<<(640000 + 255) / 256, 256, 0, stream>>>((const float4*)emb_pep, (ushort4*)emb_pep_b, 640000);
    cvt_kernel<<<(8192 + 255) / 256, 256, 0, stream>>>((const float4*)proj_W, (ushort4*)proj_W_b, 8192);
    cvt_kernel<<<(8192 + 255) / 256, 256, 0, stream>>>((const float4*)l1_mt_Wr, (ushort4*)Wr1_b, 8192);
    cvt_kernel<<<(16384 + 255) / 256, 256, 0, stream>>>((const float4*)l2_mt_Wr, (ushort4*)Wr2_b, 16384);
    cvt_kernel<<<(49152 + 255) / 256, 256, 0, stream>>>((const float4*)head_W1, (ushort4*)W1_b, 49152);
    cvts_kernel<<<(160000 + 255) / 256, 256, 0, stream>>>((const float4*)emb_mhc, Acat1, 160000);

    // ---------------- pipeline ----------------
    // agg_pm = segsum(emb_pep[csr_pm]) ; mean_pm_b -> Acat1 cols0-127, Acat2 cols0-127
    gather_kernel<<<(NMHC + 7) / 8, 256, 0, stream>>>(rp_pm, csr_pm, emb_pep, agg_pm, NMHC);
    meanb_kernel<<<(160000 + 255) / 256, 256, 0, stream>>>((const float4*)agg_pm, cnt_pm, Acat1, Acat2, 160000);

    // layer1 [MFMA]: cols 0-255 -> mhc1 (relu) into Acat2 cols 128-383;  cols 256-511 -> Zb
    mfma_fused_kernel<256, 2, true, true><<<dim3((NMHC + 127) / 128, 4), 256, 0, stream>>>(
        NMHC, Acat1, Wcat1_b, l1_pm_bl, Acat2 + 128, 384, Zb);
    // acc_b = segsum(Zb[csr_mt])
    gatherb_kernel<<<(NTCR + 7) / 8, 256, 0, stream>>>(rp_mt, csr_mt, Zb, acc_b, NTCR);
    // tcr1_b = relu( emb_tcr_b @ Wr1^T + bl + acc_b/cnt )
    mfma_gemm_kernel<128><<<dim3((NTCR + 127) / 128, 2), 256, 0, stream>>>(
        NTCR, emb_tcr_b, Wr1_b, l1_mt_bl, cnt_mt, acc_b, tcr1_b);

    // layer2 [MFMA]: cols 0-255 -> mhc2_b (relu);  cols 256-511 -> Zb
    mfma_fused_kernel<384, 2, true, true><<<dim3((NMHC + 127) / 128, 4), 256, 0, stream>>>(
        NMHC, Acat2, Wcat2_b, l2_pm_bl, mhc2_b, 256, Zb);
    // acc_b = segsum(Zb[csr_mt])
    gatherb_kernel<<<(NTCR + 7) / 8, 256, 0, stream>>>(rp_mt, csr_mt, Zb, acc_b, NTCR);
    // tcr2_b = relu( tcr1_b @ Wr2^T + bl + acc_b/cnt )   (emb_tcr_b now dead, aliased)
    mfma_gemm_kernel<256><<<dim3((NTCR + 127) / 128, 2), 256, 0, stream>>>(
        NTCR, tcr1_b, Wr2_b, l2_mt_bl, cnt_mt, acc_b, tcr2_b);

    // hp_b = emb_pep_b @ proj_W^T + proj_b  (no relu)
    mfma_fused_kernel<128, 2, false, false><<<dim3((NPEP + 127) / 128, 2), 256, 0, stream>>>(
        NPEP, emb_pep_b, proj_W_b, proj_b, hp_b, 256, nullptr);

    // head
    mfma_head_kernel<<<(BB + 63) / 64, 256, 0, stream>>>(
        hp_b, mhc2_b, tcr2_b, pack_pep, pack_mhc, pack_tcr, W1_b, head_b1, head_W2, head_b2, out);
}

// Round 7
// 519.729 us; speedup vs baseline: 8.2554x; 1.0608x over previous
//
#include <hip/hip_runtime.h>

// ---------------- problem constants ----------------
constexpr int NPEP = 20000, NMHC = 5000, NTCR = 100000;
constexpr int EPM = 200000, EMT = 400000, BB = 50000;

typedef __attribute__((ext_vector_type(8))) short bf16x8;
typedef __attribute__((ext_vector_type(4))) float f32x4;

__device__ inline ushort f2bf(float x) {
    union { float f; unsigned u; } v; v.f = x;
    unsigned r = (v.u + 0x7FFF + ((v.u >> 16) & 1)) >> 16;
    return (ushort)r;
}
__device__ inline float bf2f(ushort b) {
    union { unsigned u; float f; } t; t.u = ((unsigned)b) << 16; return t.f;
}
__device__ inline void bf2x2(unsigned u, float& a, float& b) {
    union { unsigned x; float f; } t1, t2;
    t1.x = u << 16; t2.x = u & 0xffff0000u;
    a = t1.f; b = t2.f;
}
__device__ inline ushort4 f4bf(float4 v) {
    return make_ushort4(f2bf(v.x), f2bf(v.y), f2bf(v.z), f2bf(v.w));
}

// ---------------- merged prep kernel (block-range dispatch) ----------------
// ranges (blocks of 256 threads):
//  [0,206)        zero 210000 ints (52500 int4)
//  [206,12706)    cvt emb_tcr   (3,200,000 f4)
//  [12706,15206)  cvt emb_pep   (640,000 f4)
//  [15206,15238)  cvt l1_mt_Wr  (8192 f4)
//  [15238,15302)  cvt l2_mt_Wr  (16384 f4)
//  [15302,15366)  W1b split     (16384 f4, head_W1 cols 256..511)
//  [15366,15430)  W1c split     (16384 f4, head_W1 cols 512..767)
//  [15430,15942)  wcat1 scalar  (131072)
//  [15942,16710)  wcat2 scalar  (196608)
//  [16710,17335)  emb_mhc -> Acat1 cols 128..255 (160000 f4)
//  [17335,17591)  wcomp: Wcomp[256x128] = W1a@proj_W, bp = W1a@proj_b
__global__ __launch_bounds__(256) void prep_kernel(
    int* __restrict__ ibz,
    const float4* __restrict__ emb_tcr, ushort4* __restrict__ emb_tcr_b,
    const float4* __restrict__ emb_pep, ushort4* __restrict__ emb_pep_b,
    const float4* __restrict__ Wr1f, ushort4* __restrict__ Wr1_b,
    const float4* __restrict__ Wr2f, ushort4* __restrict__ Wr2_b,
    const float* __restrict__ head_W1, ushort4* __restrict__ W1b_b, ushort4* __restrict__ W1c_b,
    const float* __restrict__ l1_pm_Wl, const float* __restrict__ l1_pm_Wr,
    const float* __restrict__ l1_mt_Wl, ushort* __restrict__ Wcat1_b,
    const float* __restrict__ l2_pm_Wl, const float* __restrict__ l2_pm_Wr,
    const float* __restrict__ l2_mt_Wl, ushort* __restrict__ Wcat2_b,
    const float4* __restrict__ emb_mhc, ushort* __restrict__ Acat1,
    const float* __restrict__ proj_W, const float* __restrict__ proj_b,
    ushort* __restrict__ Wcomp_b, float* __restrict__ bp) {
    __shared__ float red[128];
    const int b = blockIdx.x, tid = threadIdx.x;
    if (b < 206) {
        int i = b * 256 + tid;
        if (i < 52500) ((int4*)ibz)[i] = make_int4(0, 0, 0, 0);
    } else if (b < 12706) {
        int i = (b - 206) * 256 + tid;
        if (i < 3200000) emb_tcr_b[i] = f4bf(emb_tcr[i]);
    } else if (b < 15206) {
        int i = (b - 12706) * 256 + tid;
        if (i < 640000) emb_pep_b[i] = f4bf(emb_pep[i]);
    } else if (b < 15238) {
        int i = (b - 15206) * 256 + tid;
        if (i < 8192) Wr1_b[i] = f4bf(Wr1f[i]);
    } else if (b < 15302) {
        int i = (b - 15238) * 256 + tid;
        if (i < 16384) Wr2_b[i] = f4bf(Wr2f[i]);
    } else if (b < 15366) {
        int i = (b - 15302) * 256 + tid;
        if (i < 16384) {
            int n = i >> 6, k4 = (i & 63) * 4;
            float4 v = *(const float4*)(head_W1 + (size_t)n * 768 + 256 + k4);
            W1b_b[i] = f4bf(v);
        }
    } else if (b < 15430) {
        int i = (b - 15366) * 256 + tid;
        if (i < 16384) {
            int n = i >> 6, k4 = (i & 63) * 4;
            float4 v = *(const float4*)(head_W1 + (size_t)n * 768 + 512 + k4);
            W1c_b[i] = f4bf(v);
        }
    } else if (b < 15942) {
        int idx = (b - 15430) * 256 + tid;   // 512x256
        if (idx < 131072) {
            int r = idx >> 8, k = idx & 255;
            float v;
            if (r < 256) v = (k < 128) ? l1_pm_Wl[r * 128 + k] : l1_pm_Wr[r * 128 + (k - 128)];
            else         v = (k < 128) ? 0.f : l1_mt_Wl[(r - 256) * 128 + (k - 128)];
            Wcat1_b[idx] = f2bf(v);
        }
    } else if (b < 16710) {
        int idx = (b - 15942) * 256 + tid;   // 512x384
        if (idx < 196608) {
            int r = idx / 384, k = idx - r * 384;
            float v;
            if (r < 256) v = (k < 128) ? l2_pm_Wl[r * 128 + k] : l2_pm_Wr[r * 256 + (k - 128)];
            else         v = (k < 128) ? 0.f : l2_mt_Wl[(r - 256) * 256 + (k - 128)];
            Wcat2_b[idx] = f2bf(v);
        }
    } else if (b < 17335) {
        int i4 = (b - 16710) * 256 + tid;
        if (i4 < 160000) {
            int r = i4 >> 5, c4 = (i4 & 31) * 4;
            *(ushort4*)(Acat1 + (size_t)r * 256 + 128 + c4) = f4bf(emb_mhc[i4]);
        }
    } else {
        // wcomp: one block per output row i (0..255); threads 0..127 -> j
        int i = b - 17335;
        const float* w1row = head_W1 + (size_t)i * 768;
        if (tid < 128) {
            float acc = 0.f;
            for (int k = 0; k < 256; k++) acc += w1row[k] * proj_W[k * 128 + tid];
            Wcomp_b[i * 128 + tid] = f2bf(acc);
            // bp partial
            float pb = w1row[2 * tid] * proj_b[2 * tid] + w1row[2 * tid + 1] * proj_b[2 * tid + 1];
            red[tid] = pb;
        }
        __syncthreads();
        if (tid < 64) { red[tid] += red[tid + 64]; }
        __syncthreads();
        if (tid < 32) { red[tid] += red[tid + 32]; }
        __syncthreads();
        if (tid == 0) {
            float s = 0.f;
            for (int j = 0; j < 32; j++) s += red[j];
            bp[i] = s;
        }
    }
}

// ---------------- merged histogram (both relations) ----------------
__global__ void hist2_kernel(const int* __restrict__ dst_pm, const int* __restrict__ dst_mt,
                             int* __restrict__ deg_pm, int* __restrict__ deg_mt) {
    int t = blockIdx.x * blockDim.x + threadIdx.x;
    if (t < EPM) atomicAdd(&deg_pm[dst_pm[t]], 1);
    else if (t < EPM + EMT) atomicAdd(&deg_mt[dst_mt[t - EPM]], 1);
}

// ---------------- merged blocksum: blocks [0,5) pm, [5,103) mt ----------------
__global__ __launch_bounds__(256) void blocksum2_kernel(const int* __restrict__ deg_pm,
                                                        const int* __restrict__ deg_mt,
                                                        int* __restrict__ bsum_pm,
                                                        int* __restrict__ bsum_mt) {
    __shared__ int red[256];
    const int tid = threadIdx.x;
    const int* deg; int n, bi; int* bsum;
    if (blockIdx.x < 5) { deg = deg_pm; n = NMHC; bi = blockIdx.x; bsum = bsum_pm; }
    else { deg = deg_mt; n = NTCR; bi = blockIdx.x - 5; bsum = bsum_mt; }
    const int base = bi * 1024;
    int s = 0;
#pragma unroll
    for (int j = 0; j < 4; j++) {
        int i = base + tid + j * 256;
        if (i < n) s += deg[i];
    }
    red[tid] = s;
    __syncthreads();
    for (int off = 128; off > 0; off >>= 1) {
        if (tid < off) red[tid] += red[tid + off];
        __syncthreads();
    }
    if (tid == 0) bsum[bi] = red[0];
}

// ---------------- merged scan of block sums: block 0 pm (nb=5), block 1 mt (nb=98) ----------------
__global__ __launch_bounds__(128) void scanb2_kernel(int* __restrict__ bsum_pm,
                                                     int* __restrict__ bsum_mt) {
    __shared__ int s[128];
    const int tid = threadIdx.x;
    int* bsum = (blockIdx.x == 0) ? bsum_pm : bsum_mt;
    const int nb = (blockIdx.x == 0) ? 5 : 98;
    int v = (tid < nb) ? bsum[tid] : 0;
    s[tid] = v;
    __syncthreads();
    for (int off = 1; off < 128; off <<= 1) {
        int t = (tid >= off) ? s[tid - off] : 0;
        __syncthreads();
        s[tid] += t;
        __syncthreads();
    }
    if (tid < nb) bsum[tid] = (tid > 0) ? s[tid - 1] : 0;
    if (tid == 0) bsum[nb] = s[nb - 1];
}

// ---------------- merged emit: blocks [0,5) pm, [5,103) mt ----------------
__global__ __launch_bounds__(256) void emit2_kernel(const int* __restrict__ deg_pm,
                                                    const int* __restrict__ deg_mt,
                                                    const int* __restrict__ bsum_pm,
                                                    const int* __restrict__ bsum_mt,
                                                    int* __restrict__ rp_pm, float* __restrict__ cnt_pm,
                                                    int* __restrict__ rp_mt, float* __restrict__ cnt_mt) {
    __shared__ int tsum[256];
    const int tid = threadIdx.x;
    const int* deg; const int* bsum; int* rp; float* cnt; int n, nb, bi;
    if (blockIdx.x < 5) { deg = deg_pm; bsum = bsum_pm; rp = rp_pm; cnt = cnt_pm; n = NMHC; nb = 5; bi = blockIdx.x; }
    else { deg = deg_mt; bsum = bsum_mt; rp = rp_mt; cnt = cnt_mt; n = NTCR; nb = 98; bi = blockIdx.x - 5; }
    const int i0 = bi * 1024 + tid * 4;
    int4 v = make_int4(0, 0, 0, 0);
    if (i0 + 3 < n) v = *(const int4*)(deg + i0);
    else if (i0 < n) {
        int t[4] = {0, 0, 0, 0};
        for (int j = 0; j < 4 && i0 + j < n; j++) t[j] = deg[i0 + j];
        v = make_int4(t[0], t[1], t[2], t[3]);
    }
    int s = v.x + v.y + v.z + v.w;
    tsum[tid] = s;
    __syncthreads();
    for (int off = 1; off < 256; off <<= 1) {
        int t = (tid >= off) ? tsum[tid - off] : 0;
        __syncthreads();
        tsum[tid] += t;
        __syncthreads();
    }
    int ex = ((tid > 0) ? tsum[tid - 1] : 0) + bsum[bi];
    if (i0 + 3 < n) {
        int r1 = ex + v.x, r2 = r1 + v.y, r3 = r2 + v.z;
        *(int4*)(rp + i0) = make_int4(ex, r1, r2, r3);
        *(float4*)(cnt + i0) = make_float4((float)v.x, (float)v.y, (float)v.z, (float)v.w);
    } else if (i0 < n) {
        int r = ex;
        int vv[4] = {v.x, v.y, v.z, v.w};
        for (int j = 0; j < 4 && i0 + j < n; j++) {
            rp[i0 + j] = r;
            cnt[i0 + j] = (float)vv[j];
            r += vv[j];
        }
    }
    if (bi == 0 && tid == 0) rp[n] = bsum[nb];
}

// ---------------- merged CSR fill ----------------
__global__ void fill2_kernel(const int* __restrict__ src_pm, const int* __restrict__ dst_pm,
                             const int* __restrict__ src_mt, const int* __restrict__ dst_mt,
                             const int* __restrict__ rp_pm, int* __restrict__ cur_pm, int* __restrict__ csr_pm,
                             const int* __restrict__ rp_mt, int* __restrict__ cur_mt, int* __restrict__ csr_mt) {
    int t = blockIdx.x * blockDim.x + threadIdx.x;
    if (t < EPM) {
        int d = dst_pm[t];
        int pos = atomicAdd(&cur_pm[d], 1);
        csr_pm[rp_pm[d] + pos] = src_pm[t];
    } else if (t < EPM + EMT) {
        int t2 = t - EPM;
        int d = dst_mt[t2];
        int pos = atomicAdd(&cur_mt[d], 1);
        csr_mt[rp_mt[d] + pos] = src_mt[t2];
    }
}

// ---------------- pm gather + mean -> bf16 into Acat1 cols0-127 & Acat2 cols0-127 ----------------
__global__ __launch_bounds__(256) void gatherpm_kernel(const int* __restrict__ rp,
                                                       const int* __restrict__ csr_src,
                                                       const float* __restrict__ X,
                                                       ushort* __restrict__ A1, ushort* __restrict__ A2,
                                                       int n) {
    const int tid = threadIdx.x;
    const int r = blockIdx.x * 8 + (tid >> 5);
    const int lane = tid & 31;
    if (r >= n) return;
    const int e0 = rp[r], e1 = rp[r + 1];
    float4 s = make_float4(0.f, 0.f, 0.f, 0.f);
    for (int e = e0; e < e1; e++) {
        const int sidx = csr_src[e];
        float4 v = ((const float4*)(X + (long)sidx * 128))[lane];
        s.x += v.x; s.y += v.y; s.z += v.z; s.w += v.w;
    }
    float sc = 1.f / fmaxf((float)(e1 - e0), 1.f);
    ushort4 o = make_ushort4(f2bf(s.x * sc), f2bf(s.y * sc), f2bf(s.z * sc), f2bf(s.w * sc));
    *(ushort4*)(A1 + (size_t)r * 256 + lane * 4) = o;
    *(ushort4*)(A2 + (size_t)r * 384 + lane * 4) = o;
}

// ---------------- bf16 pull gather (mt relation, D=256 bf16 in/out) ----------------
__global__ __launch_bounds__(256) void gatherb_kernel(const int* __restrict__ rp,
                                                      const int* __restrict__ csr_src,
                                                      const ushort* __restrict__ Zb,
                                                      ushort* __restrict__ accb, int n) {
    const int tid = threadIdx.x;
    const int r = blockIdx.x * 8 + (tid >> 5);
    const int lane = tid & 31;
    if (r >= n) return;
    const int e0 = rp[r], e1 = rp[r + 1];
    float s[8] = {};
    for (int e = e0; e < e1; e++) {
        const int sidx = csr_src[e];
        uint4 u = *(const uint4*)(Zb + (size_t)sidx * 256 + lane * 8);
        float a, b;
        bf2x2(u.x, a, b); s[0] += a; s[1] += b;
        bf2x2(u.y, a, b); s[2] += a; s[3] += b;
        bf2x2(u.z, a, b); s[4] += a; s[5] += b;
        bf2x2(u.w, a, b); s[6] += a; s[7] += b;
    }
    ushort o[8];
#pragma unroll
    for (int j = 0; j < 8; j++) o[j] = f2bf(s[j]);
    uint4 w;
    w.x = (unsigned)o[0] | ((unsigned)o[1] << 16);
    w.y = (unsigned)o[2] | ((unsigned)o[3] << 16);
    w.z = (unsigned)o[4] | ((unsigned)o[5] << 16);
    w.w = (unsigned)o[6] | ((unsigned)o[7] << 16);
    *(uint4*)(accb + (size_t)r * 256 + lane * 8) = w;
}

// ---------------- bf16 MFMA fused GEMM (layer1/layer2): dual bf16 outputs ----------------
template <int K, int NB0, bool RELU0, bool G2>
__global__ __launch_bounds__(256, 2) void mfma_fused_kernel(
    int M, const ushort* __restrict__ A, const ushort* __restrict__ W,
    const float* __restrict__ bias,
    ushort* __restrict__ out0, int s0, ushort* __restrict__ out1) {
    constexpr int RS = 40;
    __shared__ ushort Als[128 * RS];
    __shared__ ushort Wls[128 * RS];
    const int tid = threadIdx.x;
    const int m0 = blockIdx.x * 128, n0 = blockIdx.y * 128;
    const int lane = tid & 63, w = tid >> 6;
    const int wm = w >> 1, wn = w & 1;
    const int m16 = lane & 15, q = lane >> 4;

    f32x4 acc[4][4] = {};

    for (int k0 = 0; k0 < K; k0 += 32) {
        bf16x8 a_st[2], w_st[2];
#pragma unroll
        for (int r = 0; r < 2; r++) {
            int chunk = tid + r * 256;
            int row = chunk >> 2, off = (chunk & 3) * 8;
            int ga = min(m0 + row, M - 1);
            a_st[r] = *(const bf16x8*)(A + (size_t)ga * K + k0 + off);
            w_st[r] = *(const bf16x8*)(W + (size_t)(n0 + row) * K + k0 + off);
        }
        __syncthreads();
#pragma unroll
        for (int r = 0; r < 2; r++) {
            int chunk = tid + r * 256;
            int row = chunk >> 2, off = (chunk & 3) * 8;
            *(bf16x8*)(&Als[row * RS + off]) = a_st[r];
            *(bf16x8*)(&Wls[row * RS + off]) = w_st[r];
        }
        __syncthreads();
        bf16x8 af[4], bf[4];
#pragma unroll
        for (int t = 0; t < 4; t++) {
            af[t] = *(const bf16x8*)(&Als[(wm * 64 + t * 16 + m16) * RS + q * 8]);
            bf[t] = *(const bf16x8*)(&Wls[(wn * 64 + t * 16 + m16) * RS + q * 8]);
        }
#pragma unroll
        for (int mt = 0; mt < 4; mt++)
#pragma unroll
            for (int nt = 0; nt < 4; nt++)
                acc[mt][nt] = __builtin_amdgcn_mfma_f32_16x16x32_bf16(af[mt], bf[nt], acc[mt][nt], 0, 0, 0);
    }

    const bool g1 = G2 && ((int)blockIdx.y >= NB0);
#pragma unroll
    for (int mt = 0; mt < 4; mt++) {
#pragma unroll
        for (int i = 0; i < 4; i++) {
            int row = m0 + wm * 64 + mt * 16 + q * 4 + i;
            if (row >= M) continue;
#pragma unroll
            for (int nt = 0; nt < 4; nt++) {
                int col = n0 + wn * 64 + nt * 16 + m16;
                float v = acc[mt][nt][i];
                if (!g1) {
                    v += bias[col];
                    if (RELU0) v = fmaxf(v, 0.f);
                    out0[(size_t)row * s0 + col] = f2bf(v);
                } else {
                    out1[(size_t)row * 256 + (col - NB0 * 128)] = f2bf(v);
                }
            }
        }
    }
}

// ---------------- bf16 MFMA GEMM (tcr): Cb = relu(A@W^T + bias + bf16acc/cnt) ----------------
template <int K>
__global__ __launch_bounds__(256, 2) void mfma_gemm_kernel(
    int M, const ushort* __restrict__ A, const ushort* __restrict__ W,
    const float* __restrict__ bias, const float* __restrict__ cnt,
    const ushort* __restrict__ accp, ushort* __restrict__ Cb) {
    constexpr int RS = 40;
    __shared__ ushort Als[128 * RS];
    __shared__ ushort Wls[128 * RS];
    const int tid = threadIdx.x;
    const int m0 = blockIdx.x * 128, n0 = blockIdx.y * 128;
    const int lane = tid & 63, w = tid >> 6;
    const int wm = w >> 1, wn = w & 1;
    const int m16 = lane & 15, q = lane >> 4;

    f32x4 acc[4][4] = {};

    for (int k0 = 0; k0 < K; k0 += 32) {
        bf16x8 a_st[2], w_st[2];
#pragma unroll
        for (int r = 0; r < 2; r++) {
            int chunk = tid + r * 256;
            int row = chunk >> 2, off = (chunk & 3) * 8;
            int ga = min(m0 + row, M - 1);
            a_st[r] = *(const bf16x8*)(A + (size_t)ga * K + k0 + off);
            w_st[r] = *(const bf16x8*)(W + (size_t)(n0 + row) * K + k0 + off);
        }
        __syncthreads();
#pragma unroll
        for (int r = 0; r < 2; r++) {
            int chunk = tid + r * 256;
            int row = chunk >> 2, off = (chunk & 3) * 8;
            *(bf16x8*)(&Als[row * RS + off]) = a_st[r];
            *(bf16x8*)(&Wls[row * RS + off]) = w_st[r];
        }
        __syncthreads();
        bf16x8 af[4], bf[4];
#pragma unroll
        for (int t = 0; t < 4; t++) {
            af[t] = *(const bf16x8*)(&Als[(wm * 64 + t * 16 + m16) * RS + q * 8]);
            bf[t] = *(const bf16x8*)(&Wls[(wn * 64 + t * 16 + m16) * RS + q * 8]);
        }
#pragma unroll
        for (int mt = 0; mt < 4; mt++)
#pragma unroll
            for (int nt = 0; nt < 4; nt++)
                acc[mt][nt] = __builtin_amdgcn_mfma_f32_16x16x32_bf16(af[mt], bf[nt], acc[mt][nt], 0, 0, 0);
    }

#pragma unroll
    for (int mt = 0; mt < 4; mt++) {
#pragma unroll
        for (int i = 0; i < 4; i++) {
            int row = m0 + wm * 64 + mt * 16 + q * 4 + i;
            if (row >= M) continue;
            float es = 1.f / fmaxf(cnt[row], 1.f);
#pragma unroll
            for (int nt = 0; nt < 4; nt++) {
                int col = n0 + wn * 64 + nt * 16 + m16;
                float v = acc[mt][nt][i] + bias[col] + bf2f(accp[(size_t)row * 256 + col]) * es;
                Cb[(size_t)row * 256 + col] = f2bf(fmaxf(v, 0.f));
            }
        }
    }
}

// ---------------- bf16 MFMA GEMM, fp32 single output (H tables) ----------------
template <int K, bool HASB>
__global__ __launch_bounds__(256, 2) void mfma_out_kernel(
    int M, const ushort* __restrict__ A, const ushort* __restrict__ W,
    const float* __restrict__ bias, float* __restrict__ out) {
    constexpr int RS = 40;
    __shared__ ushort Als[128 * RS];
    __shared__ ushort Wls[128 * RS];
    const int tid = threadIdx.x;
    const int m0 = blockIdx.x * 128, n0 = blockIdx.y * 128;
    const int lane = tid & 63, w = tid >> 6;
    const int wm = w >> 1, wn = w & 1;
    const int m16 = lane & 15, q = lane >> 4;

    f32x4 acc[4][4] = {};

    for (int k0 = 0; k0 < K; k0 += 32) {
        bf16x8 a_st[2], w_st[2];
#pragma unroll
        for (int r = 0; r < 2; r++) {
            int chunk = tid + r * 256;
            int row = chunk >> 2, off = (chunk & 3) * 8;
            int ga = min(m0 + row, M - 1);
            a_st[r] = *(const bf16x8*)(A + (size_t)ga * K + k0 + off);
            w_st[r] = *(const bf16x8*)(W + (size_t)(n0 + row) * K + k0 + off);
        }
        __syncthreads();
#pragma unroll
        for (int r = 0; r < 2; r++) {
            int chunk = tid + r * 256;
            int row = chunk >> 2, off = (chunk & 3) * 8;
            *(bf16x8*)(&Als[row * RS + off]) = a_st[r];
            *(bf16x8*)(&Wls[row * RS + off]) = w_st[r];
        }
        __syncthreads();
        bf16x8 af[4], bf[4];
#pragma unroll
        for (int t = 0; t < 4; t++) {
            af[t] = *(const bf16x8*)(&Als[(wm * 64 + t * 16 + m16) * RS + q * 8]);
            bf[t] = *(const bf16x8*)(&Wls[(wn * 64 + t * 16 + m16) * RS + q * 8]);
        }
#pragma unroll
        for (int mt = 0; mt < 4; mt++)
#pragma unroll
            for (int nt = 0; nt < 4; nt++)
                acc[mt][nt] = __builtin_amdgcn_mfma_f32_16x16x32_bf16(af[mt], bf[nt], acc[mt][nt], 0, 0, 0);
    }

#pragma unroll
    for (int mt = 0; mt < 4; mt++) {
#pragma unroll
        for (int i = 0; i < 4; i++) {
            int row = m0 + wm * 64 + mt * 16 + q * 4 + i;
            if (row >= M) continue;
#pragma unroll
            for (int nt = 0; nt < 4; nt++) {
                int col = n0 + wn * 64 + nt * 16 + m16;
                float v = acc[mt][nt][i];
                if (HASB) v += bias[col];
                out[(size_t)row * 256 + col] = v;
            }
        }
    }
}

// ---------------- combine: out[i] = relu(Hp[pp]+Hm[pm]+Ht[pt]+b1) . W2 + b2 ----------------
// one wave per triplet x 8 triplets per wave, 4 waves/block
__global__ __launch_bounds__(256) void combine_kernel(
    const float* __restrict__ Hp, const float* __restrict__ Hm, const float* __restrict__ Ht,
    const int* __restrict__ pp, const int* __restrict__ pm, const int* __restrict__ pt,
    const float* __restrict__ b1, const float* __restrict__ W2, const float* __restrict__ b2,
    float* __restrict__ out) {
    const int tid = threadIdx.x;
    const int lane = tid & 63, w = tid >> 6;
    const int c = lane * 4;
    const float4 b1v = *(const float4*)(b1 + c);
    const float4 w2v = *(const float4*)(W2 + c);
    const float b2v = b2[0];
    const int base = blockIdx.x * 32 + w * 8;
#pragma unroll
    for (int t = 0; t < 8; t++) {
        int i = base + t;
        if (i >= BB) return;
        int ra = pp[i], rb = pm[i], rc = pt[i];
        float4 a = *(const float4*)(Hp + (size_t)ra * 256 + c);
        float4 bq = *(const float4*)(Hm + (size_t)rb * 256 + c);
        float4 cq = *(const float4*)(Ht + (size_t)rc * 256 + c);
        float h0 = fmaxf(a.x + bq.x + cq.x + b1v.x, 0.f);
        float h1 = fmaxf(a.y + bq.y + cq.y + b1v.y, 0.f);
        float h2 = fmaxf(a.z + bq.z + cq.z + b1v.z, 0.f);
        float h3 = fmaxf(a.w + bq.w + cq.w + b1v.w, 0.f);
        float p = h0 * w2v.x + h1 * w2v.y + h2 * w2v.z + h3 * w2v.w;
#pragma unroll
        for (int off = 32; off > 0; off >>= 1) p += __shfl_down(p, off);
        if (lane == 0) out[i] = p + b2v;
    }
}

// ---------------- launch ----------------
extern "C" void kernel_launch(void* const* d_in, const int* in_sizes, int n_in,
                              void* d_out, int out_size, void* d_ws, size_t ws_size,
                              hipStream_t stream) {
    const float* emb_pep = (const float*)d_in[0];
    const float* emb_mhc = (const float*)d_in[1];
    const float* emb_tcr = (const float*)d_in[2];
    const int* src_pm = (const int*)d_in[3];
    const int* dst_pm = (const int*)d_in[4];
    const int* src_mt = (const int*)d_in[5];
    const int* dst_mt = (const int*)d_in[6];
    const int* pack_pep = (const int*)d_in[7];
    const int* pack_mhc = (const int*)d_in[8];
    const int* pack_tcr = (const int*)d_in[9];
    const float* l1_pm_Wl = (const float*)d_in[10];
    const float* l1_pm_bl = (const float*)d_in[11];
    const float* l1_pm_Wr = (const float*)d_in[12];
    const float* l1_mt_Wl = (const float*)d_in[13];
    const float* l1_mt_bl = (const float*)d_in[14];
    const float* l1_mt_Wr = (const float*)d_in[15];
    const float* l2_pm_Wl = (const float*)d_in[16];
    const float* l2_pm_bl = (const float*)d_in[17];
    const float* l2_pm_Wr = (const float*)d_in[18];
    const float* l2_mt_Wl = (const float*)d_in[19];
    const float* l2_mt_bl = (const float*)d_in[20];
    const float* l2_mt_Wr = (const float*)d_in[21];
    const float* proj_W = (const float*)d_in[22];
    const float* proj_b = (const float*)d_in[23];
    const float* head_W1 = (const float*)d_in[24];
    const float* head_b1 = (const float*)d_in[25];
    const float* head_W2 = (const float*)d_in[26];
    const float* head_b2 = (const float*)d_in[27];
    float* out = (float*)d_out;

    // ---------------- workspace layout ----------------
    int* ib = (int*)d_ws;
    int* deg_pm = ib;                 // 5000
    int* cur_pm = ib + 5000;          // 5000
    int* deg_mt = ib + 10000;         // 100000
    int* cur_mt = ib + 110000;        // 100000   [zero region: first 210000 ints]
    int* rp_pm  = ib + 210000;        // 5001 (pad 5008)
    int* rp_mt  = ib + 215008;        // 100001 (pad 100008)
    int* csr_pm = ib + 315016;        // 200000
    int* csr_mt = ib + 515016;        // 400000
    int* bsum_pm = ib + 915016;       // 160
    int* bsum_mt = ib + 915176;       // 160 -> ints end 915336, pad 915344

    float* f = (float*)(ib + 915344);
    float* cnt_pm = f;                // 5000
    float* cnt_mt = f + 5000;         // 100000
    float* bp     = f + 105000;       // 256 (pad 320)
    float* Hp_all = f + 105344;       // 5120000
    float* Hm_all = f + 5225344;      // 1280000
    // floats end f + 6505344

    ushort* u = (ushort*)(f + 6505344);
    ushort* Wcat1_b = u;              // 131072
    ushort* Wcat2_b = u + 131072;     // 196608
    ushort* W1b_b   = u + 327680;     // 65536
    ushort* W1c_b   = u + 393216;     // 65536
    ushort* Wcomp_b = u + 458752;     // 32768
    ushort* Wr1_b   = u + 491520;     // 32768
    ushort* Wr2_b   = u + 524288;     // 65536
    ushort* Acat1   = u + 589824;     // 1280000 (5000x256: [mean_pm | emb_mhc])
    ushort* Acat2   = u + 1869824;    // 1920000 (5000x384: [mean_pm | mhc1])
    ushort* Zb      = u + 3789824;    // 1280000
    ushort* mhc2_b  = u + 5069824;    // 1280000
    ushort* emb_pep_b = u + 6349824;  // 2560000
    ushort* acc_b   = u + 8909824;    // 25600000
    ushort* tcr1_b  = u + 34509824;   // 25600000
    ushort* ushare  = u + 60109824;   // 25600000 (emb_tcr_b then tcr2_b)
    ushort* emb_tcr_b = ushare;
    ushort* tcr2_b    = ushare;
    float* Ht_all = (float*)(u + 8909824);  // aliases acc_b+tcr1_b (both dead by Ht GEMM)
    // total ~204 MB

    // ---------------- 1. merged prep ----------------
    prep_kernel<<<17591, 256, 0, stream>>>(
        ib,
        (const float4*)emb_tcr, (ushort4*)emb_tcr_b,
        (const float4*)emb_pep, (ushort4*)emb_pep_b,
        (const float4*)l1_mt_Wr, (ushort4*)Wr1_b,
        (const float4*)l2_mt_Wr, (ushort4*)Wr2_b,
        head_W1, (ushort4*)W1b_b, (ushort4*)W1c_b,
        l1_pm_Wl, l1_pm_Wr, l1_mt_Wl, Wcat1_b,
        l2_pm_Wl, l2_pm_Wr, l2_mt_Wl, Wcat2_b,
        (const float4*)emb_mhc, Acat1,
        proj_W, proj_b, Wcomp_b, bp);

    // ---------------- 2-6. CSR build ----------------
    hist2_kernel<<<(EPM + EMT + 255) / 256, 256, 0, stream>>>(dst_pm, dst_mt, deg_pm, deg_mt);
    blocksum2_kernel<<<103, 256, 0, stream>>>(deg_pm, deg_mt, bsum_pm, bsum_mt);
    scanb2_kernel<<<2, 128, 0, stream>>>(bsum_pm, bsum_mt);
    emit2_kernel<<<103, 256, 0, stream>>>(deg_pm, deg_mt, bsum_pm, bsum_mt,
                                          rp_pm, cnt_pm, rp_mt, cnt_mt);
    fill2_kernel<<<(EPM + EMT + 255) / 256, 256, 0, stream>>>(
        src_pm, dst_pm, src_mt, dst_mt, rp_pm, cur_pm, csr_pm, rp_mt, cur_mt, csr_mt);

    // ---------------- 7. pm gather + mean ----------------
    gatherpm_kernel<<<(NMHC + 7) / 8, 256, 0, stream>>>(rp_pm, csr_pm, emb_pep, Acat1, Acat2, NMHC);

    // ---------------- 8-13. GNN layers ----------------
    // layer1: cols 0-255 -> mhc1 (relu) into Acat2 cols 128-383;  cols 256-511 -> Zb
    mfma_fused_kernel<256, 2, true, true><<<dim3((NMHC + 127) / 128, 4), 256, 0, stream>>>(
        NMHC, Acat1, Wcat1_b, l1_pm_bl, Acat2 + 128, 384, Zb);
    gatherb_kernel<<<(NTCR + 7) / 8, 256, 0, stream>>>(rp_mt, csr_mt, Zb, acc_b, NTCR);
    mfma_gemm_kernel<128><<<dim3((NTCR + 127) / 128, 2), 256, 0, stream>>>(
        NTCR, emb_tcr_b, Wr1_b, l1_mt_bl, cnt_mt, acc_b, tcr1_b);
    // layer2: cols 0-255 -> mhc2_b (relu);  cols 256-511 -> Zb
    mfma_fused_kernel<384, 2, true, true><<<dim3((NMHC + 127) / 128, 4), 256, 0, stream>>>(
        NMHC, Acat2, Wcat2_b, l2_pm_bl, mhc2_b, 256, Zb);
    gatherb_kernel<<<(NTCR + 7) / 8, 256, 0, stream>>>(rp_mt, csr_mt, Zb, acc_b, NTCR);
    mfma_gemm_kernel<256><<<dim3((NTCR + 127) / 128, 2), 256, 0, stream>>>(
        NTCR, tcr1_b, Wr2_b, l2_mt_bl, cnt_mt, acc_b, tcr2_b);

    // ---------------- 14-16. H tables (fp32) ----------------
    // Hp = emb_pep_b @ Wcomp^T + bp   (proj folded into head)
    mfma_out_kernel<128, true><<<dim3((NPEP + 127) / 128, 2), 256, 0, stream>>>(
        NPEP, emb_pep_b, Wcomp_b, bp, Hp_all);
    // Hm = mhc2_b @ W1b^T
    mfma_out_kernel<256, false><<<dim3((NMHC + 127) / 128, 2), 256, 0, stream>>>(
        NMHC, mhc2_b, W1b_b, nullptr, Hm_all);
    // Ht = tcr2_b @ W1c^T   (writes over dead acc_b+tcr1_b)
    mfma_out_kernel<256, false><<<dim3((NTCR + 127) / 128, 2), 256, 0, stream>>>(
        NTCR, tcr2_b, W1c_b, nullptr, Ht_all);

    // ---------------- 17. combine ----------------
    combine_kernel<<<(BB + 31) / 32, 256, 0, stream>>>(
        Hp_all, Hm_all, Ht_all, pack_pep, pack_mhc, pack_tcr,
        head_b1, head_W2, head_b2, out);
}